// Round 8
// baseline (1734.976 us; speedup 1.0000x reference)
//
#include <hip/hip_runtime.h>
#include <hip/hip_bf16.h>
#include <cstdint>
#include <cstddef>

#define DEV __device__ __forceinline__

namespace {

constexpr int S    = 2048;
constexpr int D    = 512;
constexpr int H    = 8;
constexpr int DH   = 64;
constexpr int NL   = 6;
constexpr int MLPD = 2048;
constexpr int VOC  = 256;
constexpr float EPSF = 1e-6f;

typedef unsigned short u16;
typedef __attribute__((ext_vector_type(8))) short s8v;   // 8 x bf16 (4 VGPR)
typedef __attribute__((ext_vector_type(4))) float f4v;   // MFMA accum

DEV float u2f(u16 u){
  union { unsigned int i; float f; } t; t.i = ((unsigned int)u) << 16; return t.f;
}
DEV short bfr(float f){
  __hip_bfloat16 h = __float2bfloat16(f);
  short s; __builtin_memcpy(&s, &h, 2); return s;
}
DEV float gelu_tanh(float x){
  float x3 = x * x * x;
  return 0.5f * x * (1.f + tanhf(0.7978845608028654f * (x + 0.044715f * x3)));
}
DEV void gll16(const u16* gp, u16* lp){
  __builtin_amdgcn_global_load_lds(
      (const __attribute__((address_space(1))) unsigned int*)gp,
      (__attribute__((address_space(3))) unsigned int*)lp, 16, 0, 0);
}

// ---------------- embedding + positional --------------------------------------
__global__ void k_embed(const int* __restrict__ tokens, const float* __restrict__ emb,
                        const float* __restrict__ pos, float* __restrict__ x){
  int s = blockIdx.x;
  int tok = (s == 0) ? 0 : tokens[s - 1];
  if (tok < 0) tok = 0; if (tok >= VOC) tok = VOC - 1;
  const float* er = emb + (size_t)tok * D;
  const float* pr = pos + (size_t)s * D;
  float* xr = x + (size_t)s * D;
  for (int d = threadIdx.x; d < D; d += blockDim.x)
    xr[d] = er[d] + pr[d];
}

// ---------------- layernorm: 4 rows/block, one wave per row -------------------
__global__ __launch_bounds__(256)
void k_ln(const float* __restrict__ x, const float* __restrict__ sc,
          const float* __restrict__ bi, u16* __restrict__ out){
  int s = blockIdx.x * 4 + (threadIdx.x >> 6), t = threadIdx.x & 63;
  const float* xr = x + (size_t)s * D;
  float v[8]; float sum = 0.f, sq = 0.f;
  #pragma unroll
  for (int e = 0; e < 8; ++e){ v[e] = xr[t + 64 * e]; sum += v[e]; sq += v[e] * v[e]; }
  #pragma unroll
  for (int off = 32; off >= 1; off >>= 1){
    sum += __shfl_down(sum, off, 64);
    sq  += __shfl_down(sq,  off, 64);
  }
  sum = __shfl(sum, 0, 64); sq = __shfl(sq, 0, 64);
  float mu  = sum * (1.f / (float)D);
  float var = sq * (1.f / (float)D) - mu * mu;
  float r = rsqrtf(var + EPSF);
  u16* orow = out + (size_t)s * D;
  #pragma unroll
  for (int e = 0; e < 8; ++e){
    int d = t + 64 * e;
    orow[d] = (u16)bfr((v[e] - mu) * r * sc[d] + bi[d]);
  }
}

// ---------------- weight transpose+convert: fp32 [R][C] -> bf16 [C][R] --------
__global__ __launch_bounds__(256)
void k_wt(const float* __restrict__ src, u16* __restrict__ dst, int R, int C){
  src += (size_t)blockIdx.z * R * C;
  dst += (size_t)blockIdx.z * R * C;
  __shared__ float t[32][33];
  int c0 = blockIdx.x * 32, r0 = blockIdx.y * 32;
  int tc = threadIdx.x & 31, tr8 = threadIdx.x >> 5;    // 8 rows per pass
  #pragma unroll
  for (int rr = 0; rr < 32; rr += 8)
    t[rr + tr8][tc] = src[(size_t)(r0 + rr + tr8) * C + c0 + tc];
  __syncthreads();
  #pragma unroll
  for (int rr = 0; rr < 32; rr += 8)
    dst[(size_t)(c0 + rr + tr8) * R + r0 + tc] = (u16)bfr(t[tc][rr + tr8]);
}

// ================= NEW MFMA GEMM: A bf16 [M][K], Bt bf16 [N][K] ===============
// Tile (WM*64) x (WN*64), BK=64, WM*WN waves. LDS per operand: [row][slot^swz][8]
// (row stride 128B). Staged by global_load_lds w=16 with pre-swizzled global
// source (slot = chunk ^ (row&7)); reads use the same XOR -> 2-way (free).
template<int NW>
DEV void stage(const u16* __restrict__ src, int ldk, int r0, int k0,
               u16* __restrict__ lds, int nrows)
{
  const int w = threadIdx.x >> 6, lane = threadIdx.x & 63;
  for (int j = w; j < (nrows >> 3); j += NW){
    int row = (j << 3) + (lane >> 3);
    int g = (lane & 7) ^ (row & 7);
    gll16(src + (size_t)(r0 + row) * ldk + k0 + g * 8, lds + j * 512);
  }
}

DEV void mfma_block(const u16* __restrict__ As, const u16* __restrict__ Bs,
                    f4v (&acc)[4][4], int wr, int wc, int lr, int lg)
{
  #pragma unroll
  for (int ks = 0; ks < 2; ++ks){
    s8v af[4], bf[4];
    #pragma unroll
    for (int fi = 0; fi < 4; ++fi){
      int row = wr * 64 + fi * 16 + lr;
      int slot = ((ks << 2) + lg) ^ (row & 7);
      af[fi] = *reinterpret_cast<const s8v*>(As + row * 64 + slot * 8);
    }
    #pragma unroll
    for (int fj = 0; fj < 4; ++fj){
      int col = wc * 64 + fj * 16 + lr;
      int slot = ((ks << 2) + lg) ^ (col & 7);
      bf[fj] = *reinterpret_cast<const s8v*>(Bs + col * 64 + slot * 8);
    }
    #pragma unroll
    for (int fi = 0; fi < 4; ++fi)
      #pragma unroll
      for (int fj = 0; fj < 4; ++fj)
        acc[fi][fj] = __builtin_amdgcn_mfma_f32_16x16x32_bf16(af[fi], bf[fj], acc[fi][fj], 0, 0, 0);
  }
}

// MODE 0: Cb=bf16(acc*alpha)  1: Cb=bf16(gelu(acc+bias))  2: Cf+=acc(+bias)  3: Cf=acc+bias
template<int WM, int WN, int MODE>
__global__ __launch_bounds__(WM*WN*64)
void k_g(const u16* __restrict__ A, const u16* __restrict__ Bt,
         const float* __restrict__ bias, float* __restrict__ Cf,
         u16* __restrict__ Cb, int N, int K, float alpha)
{
  constexpr int NW = WM * WN;
  __shared__ __align__(16) u16 As[WM * 64 * 64];
  __shared__ __align__(16) u16 Bs[WN * 64 * 64];
  int nx = gridDim.x;
  int nwg = nx * gridDim.y;
  int wg = blockIdx.y * nx + blockIdx.x;
  wg = (wg & 7) * (nwg >> 3) + (wg >> 3);       // XCD swizzle (nwg % 8 == 0)
  int m0 = (wg / nx) * (WM * 64);
  int n0 = (wg % nx) * (WN * 64);
  const int w = threadIdx.x >> 6, lane = threadIdx.x & 63;
  const int wr = w / WN, wc = w % WN;
  const int lr = lane & 15, lg = lane >> 4;
  f4v acc[4][4] = {};
  for (int k0 = 0; k0 < K; k0 += 64){
    __syncthreads();
    stage<NW>(A,  K, m0, k0, As, WM * 64);
    stage<NW>(Bt, K, n0, k0, Bs, WN * 64);
    __syncthreads();
    mfma_block(As, Bs, acc, wr, wc, lr, lg);
  }
  #pragma unroll
  for (int fi = 0; fi < 4; ++fi)
    #pragma unroll
    for (int fj = 0; fj < 4; ++fj)
      #pragma unroll
      for (int r = 0; r < 4; ++r){
        int row = m0 + wr * 64 + fi * 16 + lg * 4 + r;
        int col = n0 + wc * 64 + fj * 16 + lr;
        size_t idx = (size_t)row * N + col;
        float v = acc[fi][fj][r] * alpha;
        if (MODE == 0)      Cb[idx] = (u16)bfr(v);
        else if (MODE == 1) Cb[idx] = (u16)bfr(gelu_tanh(v + bias[col]));
        else if (MODE == 2) Cf[idx] += v + (bias ? bias[col] : 0.f);
        else                Cf[idx] = v + bias[col];
      }
}

// qkv: z selects weight/output; q scaled 1/8. WM=WN=2, N=K=512.
__global__ __launch_bounds__(256)
void k_gqkv(const u16* __restrict__ A, const u16* __restrict__ BtQ,
            const u16* __restrict__ BtK, const u16* __restrict__ BtV,
            u16* __restrict__ Cq, u16* __restrict__ Ck, u16* __restrict__ Cv)
{
  __shared__ __align__(16) u16 As[128 * 64];
  __shared__ __align__(16) u16 Bs[128 * 64];
  const u16* Bt = (blockIdx.z == 0) ? BtQ : (blockIdx.z == 1 ? BtK : BtV);
  u16*       C  = (blockIdx.z == 0) ? Cq  : (blockIdx.z == 1 ? Ck  : Cv);
  float alpha   = (blockIdx.z == 0) ? 0.125f : 1.f;
  int nx = gridDim.x;
  int nwg = nx * gridDim.y;
  int wg = blockIdx.y * nx + blockIdx.x;
  wg = (wg & 7) * (nwg >> 3) + (wg >> 3);
  int m0 = (wg / nx) * 128;
  int n0 = (wg % nx) * 128;
  const int w = threadIdx.x >> 6, lane = threadIdx.x & 63;
  const int wr = w >> 1, wc = w & 1;
  const int lr = lane & 15, lg = lane >> 4;
  f4v acc[4][4] = {};
  for (int k0 = 0; k0 < D; k0 += 64){
    __syncthreads();
    stage<4>(A,  D, m0, k0, As, 128);
    stage<4>(Bt, D, n0, k0, Bs, 128);
    __syncthreads();
    mfma_block(As, Bs, acc, wr, wc, lr, lg);
  }
  #pragma unroll
  for (int fi = 0; fi < 4; ++fi)
    #pragma unroll
    for (int fj = 0; fj < 4; ++fj)
      #pragma unroll
      for (int r = 0; r < 4; ++r){
        int row = m0 + wr * 64 + fi * 16 + lg * 4 + r;
        int col = n0 + wc * 64 + fj * 16 + lr;
        C[(size_t)row * D + col] = (u16)bfr(acc[fi][fj][r] * alpha);
      }
}

// ================= OLD GEMM (round-7 fallback, fp32 B) ========================
constexpr int GSTR = 1032;

DEV void mgemm_core(const u16* __restrict__ A, const float* __restrict__ B,
                    int N, int K, int m0, int n0,
                    short* __restrict__ As, short* __restrict__ Bs,
                    f4v (&acc)[4][4])
{
  const int t = threadIdx.x;
  const int lane = t & 63;
  const int wv = t >> 6;
  const int wr = wv >> 1, wc = wv & 1;
  const int lr = lane & 15, lg = lane >> 4;
  const int ar = t >> 2, ac = t & 3;
  const int bn = t & 127, bkh = t >> 7;
  for (int k0 = 0; k0 < K; k0 += 32){
    s8v av0 = *reinterpret_cast<const s8v*>(A + (size_t)(m0 + ar) * K + k0 + ac * 8);
    s8v av1 = *reinterpret_cast<const s8v*>(A + (size_t)(m0 + ar + 64) * K + k0 + ac * 8);
    float tb[16];
    #pragma unroll
    for (int kk = 0; kk < 16; ++kk)
      tb[kk] = B[(size_t)(k0 + bkh * 16 + kk) * N + n0 + bn];
    __syncthreads();
    *reinterpret_cast<s8v*>(&As[ac * GSTR + ar * 8]) = av0;
    *reinterpret_cast<s8v*>(&As[ac * GSTR + (ar + 64) * 8]) = av1;
    s8v p0, p1;
    #pragma unroll
    for (int e = 0; e < 8; ++e){ p0[e] = bfr(tb[e]); p1[e] = bfr(tb[8 + e]); }
    *reinterpret_cast<s8v*>(&Bs[(bkh * 2 + 0) * GSTR + bn * 8]) = p0;
    *reinterpret_cast<s8v*>(&Bs[(bkh * 2 + 1) * GSTR + bn * 8]) = p1;
    __syncthreads();
    s8v af[4], bf2[4];
    #pragma unroll
    for (int fi = 0; fi < 4; ++fi)
      af[fi] = *reinterpret_cast<const s8v*>(&As[lg * GSTR + (wr * 64 + fi * 16 + lr) * 8]);
    #pragma unroll
    for (int fj = 0; fj < 4; ++fj)
      bf2[fj] = *reinterpret_cast<const s8v*>(&Bs[lg * GSTR + (wc * 64 + fj * 16 + lr) * 8]);
    #pragma unroll
    for (int fi = 0; fi < 4; ++fi)
      #pragma unroll
      for (int fj = 0; fj < 4; ++fj)
        acc[fi][fj] = __builtin_amdgcn_mfma_f32_16x16x32_bf16(af[fi], bf2[fj], acc[fi][fj], 0, 0, 0);
  }
}

template<int MODE>
__global__ __launch_bounds__(256)
void k_mgemm(const u16* __restrict__ A, const float* __restrict__ B,
             const float* __restrict__ bias, float* __restrict__ Cf,
             u16* __restrict__ Cb, int N, int K, float alpha)
{
  __shared__ __align__(16) short As[4 * GSTR];
  __shared__ __align__(16) short Bs[4 * GSTR];
  int n0 = blockIdx.x * 128, m0 = blockIdx.y * 128;
  f4v acc[4][4] = {};
  mgemm_core(A, B, N, K, m0, n0, As, Bs, acc);
  const int lane = threadIdx.x & 63, wv = threadIdx.x >> 6;
  const int wr = wv >> 1, wc = wv & 1, lr = lane & 15, lg = lane >> 4;
  #pragma unroll
  for (int fi = 0; fi < 4; ++fi)
    #pragma unroll
    for (int fj = 0; fj < 4; ++fj)
      #pragma unroll
      for (int r = 0; r < 4; ++r){
        int row = m0 + wr * 64 + fi * 16 + lg * 4 + r;
        int col = n0 + wc * 64 + fj * 16 + lr;
        size_t idx = (size_t)row * N + col;
        float v = acc[fi][fj][r] * alpha;
        if (MODE == 0)      Cb[idx] = (u16)bfr(v);
        else if (MODE == 1) Cb[idx] = (u16)bfr(gelu_tanh(v + bias[col]));
        else if (MODE == 2) Cf[idx] += v + (bias ? bias[col] : 0.f);
        else                Cf[idx] = v + bias[col];
      }
}

__global__ __launch_bounds__(256)
void k_mgemm_qkv(const u16* __restrict__ A,
                 const float* __restrict__ B0, const float* __restrict__ B1,
                 const float* __restrict__ B2,
                 u16* __restrict__ C0, u16* __restrict__ C1, u16* __restrict__ C2,
                 int N, int K)
{
  __shared__ __align__(16) short As[4 * GSTR];
  __shared__ __align__(16) short Bs[4 * GSTR];
  const float* B = (blockIdx.z == 0) ? B0 : (blockIdx.z == 1 ? B1 : B2);
  u16*        C = (blockIdx.z == 0) ? C0 : (blockIdx.z == 1 ? C1 : C2);
  float alpha   = (blockIdx.z == 0) ? 0.125f : 1.f;
  int n0 = blockIdx.x * 128, m0 = blockIdx.y * 128;
  f4v acc[4][4] = {};
  mgemm_core(A, B, N, K, m0, n0, As, Bs, acc);
  const int lane = threadIdx.x & 63, wv = threadIdx.x >> 6;
  const int wr = wv >> 1, wc = wv & 1, lr = lane & 15, lg = lane >> 4;
  #pragma unroll
  for (int fi = 0; fi < 4; ++fi)
    #pragma unroll
    for (int fj = 0; fj < 4; ++fj)
      #pragma unroll
      for (int r = 0; r < 4; ++r){
        int row = m0 + wr * 64 + fi * 16 + lg * 4 + r;
        int col = n0 + wc * 64 + fj * 16 + lr;
        C[(size_t)row * N + col] = (u16)bfr(acc[fi][fj][r] * alpha);
      }
}

// ---------------- V column mean (coalesced) -----------------------------------
__global__ __launch_bounds__(256)
void k_vmean(const u16* __restrict__ vb, float* __restrict__ vmean){
  int tc = threadIdx.x & 63, rg = threadIdx.x >> 6;
  int c = blockIdx.x * 64 + tc;
  float s = 0.f;
  for (int j = rg; j < S; j += 4) s += u2f(vb[(size_t)j * D + c]);
  __shared__ float red[4][64];
  red[rg][tc] = s;
  __syncthreads();
  if (rg == 0)
    vmean[c] = (red[0][tc] + red[1][tc] + red[2][tc] + red[3][tc]) * (1.f / (float)S);
}

// ---------------- MFMA block-sparse flash attention (verified round 7) --------
__global__ __launch_bounds__(256)
void k_mattn(const u16* __restrict__ qb, const u16* __restrict__ kb,
             const u16* __restrict__ vb, const int* __restrict__ tokens,
             const float* __restrict__ vmean, u16* __restrict__ ob)
{
  const int q0 = blockIdx.x * 64;
  const int h  = blockIdx.y;
  const int B  = q0 >> 7;
  const int half = (q0 >> 6) & 1;
  const int t = threadIdx.x, w = t >> 6, lane = t & 63;
  const int lr = lane & 15, lg = lane >> 4;

  __shared__ __align__(16) u16 Vt[64][40];
  __shared__ __align__(16) u16 Ps[4][16][40];

  const u16* qrow = qb + (size_t)(q0 + 16 * w + lr) * D + h * DH;
  s8v qf0 = *reinterpret_cast<const s8v*>(qrow + lg * 8);
  s8v qf1 = *reinterpret_cast<const s8v*>(qrow + 32 + lg * 8);

  f4v o0 = {}, o1 = {}, o2 = {}, o3 = {};
  float m[4] = {-1e30f, -1e30f, -1e30f, -1e30f};
  float l[4] = {0.f, 0.f, 0.f, 0.f};

  const int vkey = t & 31, vdq = (t >> 5) * 8;
  const int ntiles = B + (half ? 4 : 2);

  for (int tt = 0; tt < ntiles; ++tt){
    int kbase; bool causal;
    if (tt < B){ kbase = tt * 128 + 96; causal = false; }
    else       { kbase = B * 128 + (tt - B) * 32; causal = (kbase >= q0); }

    __syncthreads();
    s8v vv = *reinterpret_cast<const s8v*>(vb + (size_t)(kbase + vkey) * D + h * DH + vdq);
    #pragma unroll
    for (int e = 0; e < 8; ++e) Vt[vdq + e][vkey] = (u16)vv[e];
    __syncthreads();

    f4v s0 = {}, s1 = {};
    const u16* k0p = kb + (size_t)(kbase + lr) * D + h * DH;
    const u16* k1p = kb + (size_t)(kbase + 16 + lr) * D + h * DH;
    s8v kf;
    kf = *reinterpret_cast<const s8v*>(k0p + lg * 8);
    s0 = __builtin_amdgcn_mfma_f32_16x16x32_bf16(qf0, kf, s0, 0, 0, 0);
    kf = *reinterpret_cast<const s8v*>(k0p + 32 + lg * 8);
    s0 = __builtin_amdgcn_mfma_f32_16x16x32_bf16(qf1, kf, s0, 0, 0, 0);
    kf = *reinterpret_cast<const s8v*>(k1p + lg * 8);
    s1 = __builtin_amdgcn_mfma_f32_16x16x32_bf16(qf0, kf, s1, 0, 0, 0);
    kf = *reinterpret_cast<const s8v*>(k1p + 32 + lg * 8);
    s1 = __builtin_amdgcn_mfma_f32_16x16x32_bf16(qf1, kf, s1, 0, 0, 0);

    const int tok0 = tokens[kbase + lr] > 0;
    const int tok1 = tokens[kbase + 16 + lr] > 0;
    #pragma unroll
    for (int r = 0; r < 4; ++r){
      int qg = q0 + 16 * w + 4 * lg + r;
      float a0 = (tok0 && (!causal || kbase + lr <= qg))      ? s0[r] : -1e30f;
      float a1 = (tok1 && (!causal || kbase + 16 + lr <= qg)) ? s1[r] : -1e30f;
      float tm = fmaxf(a0, a1);
      tm = fmaxf(tm, __shfl_xor(tm, 1, 64));
      tm = fmaxf(tm, __shfl_xor(tm, 2, 64));
      tm = fmaxf(tm, __shfl_xor(tm, 4, 64));
      tm = fmaxf(tm, __shfl_xor(tm, 8, 64));
      float mn = fmaxf(m[r], tm);
      bool dead = (mn <= -1e29f);
      float sc = dead ? 1.f : __expf(m[r] - mn);
      float p0 = dead ? 0.f : __expf(a0 - mn);
      float p1 = dead ? 0.f : __expf(a1 - mn);
      l[r] = l[r] * sc + p0 + p1;
      m[r] = mn;
      o0[r] *= sc; o1[r] *= sc; o2[r] *= sc; o3[r] *= sc;
      Ps[w][4 * lg + r][lr]      = (u16)bfr(p0);
      Ps[w][4 * lg + r][16 + lr] = (u16)bfr(p1);
    }

    asm volatile("s_waitcnt lgkmcnt(0)" ::: "memory");
    __builtin_amdgcn_sched_barrier(0);
    s8v pf  = *reinterpret_cast<const s8v*>(&Ps[w][lr][lg * 8]);
    s8v vf0 = *reinterpret_cast<const s8v*>(&Vt[lr][lg * 8]);
    s8v vf1 = *reinterpret_cast<const s8v*>(&Vt[16 + lr][lg * 8]);
    s8v vf2 = *reinterpret_cast<const s8v*>(&Vt[32 + lr][lg * 8]);
    s8v vf3 = *reinterpret_cast<const s8v*>(&Vt[48 + lr][lg * 8]);
    o0 = __builtin_amdgcn_mfma_f32_16x16x32_bf16(pf, vf0, o0, 0, 0, 0);
    o1 = __builtin_amdgcn_mfma_f32_16x16x32_bf16(pf, vf1, o1, 0, 0, 0);
    o2 = __builtin_amdgcn_mfma_f32_16x16x32_bf16(pf, vf2, o2, 0, 0, 0);
    o3 = __builtin_amdgcn_mfma_f32_16x16x32_bf16(pf, vf3, o3, 0, 0, 0);
  }

  #pragma unroll
  for (int r = 0; r < 4; ++r){
    float lt = l[r];
    lt += __shfl_xor(lt, 1, 64);
    lt += __shfl_xor(lt, 2, 64);
    lt += __shfl_xor(lt, 4, 64);
    lt += __shfl_xor(lt, 8, 64);
    int qg = q0 + 16 * w + 4 * lg + r;
    u16* orow = ob + (size_t)qg * D + h * DH;
    bool dead = (lt <= 0.f);
    float inv = dead ? 0.f : 1.f / lt;
    orow[lr]      = (u16)bfr(dead ? vmean[h * DH + lr]      : o0[r] * inv);
    orow[16 + lr] = (u16)bfr(dead ? vmean[h * DH + 16 + lr] : o1[r] * inv);
    orow[32 + lr] = (u16)bfr(dead ? vmean[h * DH + 32 + lr] : o2[r] * inv);
    orow[48 + lr] = (u16)bfr(dead ? vmean[h * DH + 48 + lr] : o3[r] * inv);
  }
}

} // anonymous namespace

extern "C" void kernel_launch(void* const* d_in, const int* in_sizes, int n_in,
                              void* d_out, int out_size, void* d_ws, size_t ws_size,
                              hipStream_t stream)
{
  (void)n_in; (void)out_size;

  int I_tok=0, I_emb=1, I_pos=2, I_l1s=3, I_l1b=4, I_wq=5, I_wk=6, I_wv=7,
      I_wo=8, I_l2s=9, I_l2b=10, I_w1=11, I_b1=12, I_w2=13, I_b2=14,
      I_lfs=15, I_lfb=16, I_wout=17, I_bout=18;
  if (in_sizes[0] != S){
    I_b1=0;  I_b2=1;  I_bout=2; I_emb=3;  I_l1b=4; I_l1s=5;  I_l2b=6;
    I_l2s=7; I_lfb=8; I_lfs=9;  I_pos=10; I_tok=11; I_w1=12; I_w2=13;
    I_wk=14; I_wo=15; I_wout=16; I_wq=17; I_wv=18;
  }

  const int*   tokens = (const int*)d_in[I_tok];
  const float* emb  = (const float*)d_in[I_emb];
  const float* pos  = (const float*)d_in[I_pos];
  const float* ln1s = (const float*)d_in[I_l1s];
  const float* ln1b = (const float*)d_in[I_l1b];
  const float* wq   = (const float*)d_in[I_wq];
  const float* wk   = (const float*)d_in[I_wk];
  const float* wv   = (const float*)d_in[I_wv];
  const float* wo   = (const float*)d_in[I_wo];
  const float* ln2s = (const float*)d_in[I_l2s];
  const float* ln2b = (const float*)d_in[I_l2b];
  const float* w1   = (const float*)d_in[I_w1];
  const float* b1   = (const float*)d_in[I_b1];
  const float* w2   = (const float*)d_in[I_w2];
  const float* b2   = (const float*)d_in[I_b2];
  const float* lnfs = (const float*)d_in[I_lfs];
  const float* lnfb = (const float*)d_in[I_lfb];
  const float* wout = (const float*)d_in[I_wout];
  const float* bout = (const float*)d_in[I_bout];
  float* outp = (float*)d_out;

  char* ws = (char*)d_ws;
  float* x  = (float*)(ws);
  u16*   hb = (u16*)(ws + ((size_t)4  << 20));
  u16*   qb = (u16*)(ws + ((size_t)6  << 20));
  u16*   kb = (u16*)(ws + ((size_t)8  << 20));
  u16*   vb = (u16*)(ws + ((size_t)10 << 20));
  u16*   ob = (u16*)(ws + ((size_t)12 << 20));
  u16*   gb = (u16*)(ws + ((size_t)14 << 20));
  float* vmean = (float*)(ws + ((size_t)22 << 20));

  const bool big = ws_size >= ((size_t)60 << 20);

  k_embed<<<dim3(S), dim3(128), 0, stream>>>(tokens, emb, pos, x);

  if (big){
    // transposed bf16 weights in ws
    u16* wqT  = (u16*)(ws + ((size_t)23 << 20));
    u16* wkT  = (u16*)(ws + ((size_t)26 << 20));
    u16* wvT  = (u16*)(ws + ((size_t)29 << 20));
    u16* woT  = (u16*)(ws + ((size_t)32 << 20));
    u16* w1T  = (u16*)(ws + ((size_t)35 << 20));
    u16* w2T  = (u16*)(ws + ((size_t)47 << 20));
    u16* woutT= (u16*)(ws + ((size_t)59 << 20));

    k_wt<<<dim3(16, 16, 6), dim3(256), 0, stream>>>(wq, wqT, 512, 512);
    k_wt<<<dim3(16, 16, 6), dim3(256), 0, stream>>>(wk, wkT, 512, 512);
    k_wt<<<dim3(16, 16, 6), dim3(256), 0, stream>>>(wv, wvT, 512, 512);
    k_wt<<<dim3(16, 16, 6), dim3(256), 0, stream>>>(wo, woT, 512, 512);
    k_wt<<<dim3(64, 16, 6), dim3(256), 0, stream>>>(w1, w1T, 512, 2048);
    k_wt<<<dim3(16, 64, 6), dim3(256), 0, stream>>>(w2, w2T, 2048, 512);
    k_wt<<<dim3(8,  16, 1), dim3(256), 0, stream>>>(wout, woutT, 512, 256);

    for (int l = 0; l < NL; ++l){
      size_t o512 = (size_t)l * 512 * 512, oM = (size_t)l * 512 * 2048;
      k_ln<<<dim3(S/4), dim3(256), 0, stream>>>(x, ln1s + (size_t)l*D, ln1b + (size_t)l*D, hb);
      k_gqkv<<<dim3(4, 16, 3), dim3(256), 0, stream>>>(
          hb, wqT + o512, wkT + o512, wvT + o512, qb, kb, vb);
      k_vmean<<<dim3(8), dim3(256), 0, stream>>>(vb, vmean);
      k_mattn<<<dim3(S/64, H), dim3(256), 0, stream>>>(qb, kb, vb, tokens, vmean, ob);
      k_g<1,2,2><<<dim3(4, 32), dim3(128), 0, stream>>>(
          ob, woT + o512, nullptr, x, nullptr, 512, 512, 1.f);
      k_ln<<<dim3(S/4), dim3(256), 0, stream>>>(x, ln2s + (size_t)l*D, ln2b + (size_t)l*D, hb);
      k_g<2,2,1><<<dim3(16, 16), dim3(256), 0, stream>>>(
          hb, w1T + oM, b1 + (size_t)l*MLPD, nullptr, gb, MLPD, 512, 1.f);
      k_g<1,2,2><<<dim3(4, 32), dim3(128), 0, stream>>>(
          gb, w2T + oM, b2 + (size_t)l*D, x, nullptr, 512, 2048, 1.f);
    }
    k_ln<<<dim3(S/4), dim3(256), 0, stream>>>(x, lnfs, lnfb, hb);
    k_g<1,2,3><<<dim3(2, 32), dim3(128), 0, stream>>>(
        hb, woutT, bout, outp, nullptr, VOC, 512, 1.f);
  } else {
    // round-7 fallback (fp32 weights in-GEMM)
    for (int l = 0; l < NL; ++l){
      size_t wOff = (size_t)l * D * D;
      k_ln<<<dim3(S/4), dim3(256), 0, stream>>>(x, ln1s + (size_t)l*D, ln1b + (size_t)l*D, hb);
      k_mgemm_qkv<<<dim3(4, 16, 3), dim3(256), 0, stream>>>(
          hb, wq + wOff, wk + wOff, wv + wOff, qb, kb, vb, D, D);
      k_vmean<<<dim3(8), dim3(256), 0, stream>>>(vb, vmean);
      k_mattn<<<dim3(S/64, H), dim3(256), 0, stream>>>(qb, kb, vb, tokens, vmean, ob);
      k_mgemm<2><<<dim3(4, 16), dim3(256), 0, stream>>>(
          ob, wo + wOff, nullptr, x, nullptr, D, D, 1.f);
      k_ln<<<dim3(S/4), dim3(256), 0, stream>>>(x, ln2s + (size_t)l*D, ln2b + (size_t)l*D, hb);
      k_mgemm<1><<<dim3(16, 16), dim3(256), 0, stream>>>(
          hb, w1 + (size_t)l*D*MLPD, b1 + (size_t)l*MLPD, nullptr, gb, MLPD, D, 1.f);
      k_mgemm<2><<<dim3(4, 16), dim3(256), 0, stream>>>(
          gb, w2 + (size_t)l*MLPD*D, b2 + (size_t)l*D, x, nullptr, D, MLPD, 1.f);
    }
    k_ln<<<dim3(S/4), dim3(256), 0, stream>>>(x, lnfs, lnfb, hb);
    k_mgemm<3><<<dim3(2, 16), dim3(256), 0, stream>>>(
        hb, wout, bout, outp, nullptr, VOC, D, 1.f);
  }
}

// Round 9
// 1086.385 us; speedup vs baseline: 1.5970x; 1.5970x over previous
//
#include <hip/hip_runtime.h>
#include <hip/hip_bf16.h>
#include <cstdint>
#include <cstddef>

#define DEV __device__ __forceinline__

namespace {

constexpr int S    = 2048;
constexpr int D    = 512;
constexpr int H    = 8;
constexpr int DH   = 64;
constexpr int NL   = 6;
constexpr int MLPD = 2048;
constexpr int VOC  = 256;
constexpr int QS   = 1536;   // fused qkv row stride
constexpr float EPSF = 1e-6f;

typedef unsigned short u16;
typedef __attribute__((ext_vector_type(8))) short s8v;   // 8 x bf16 (4 VGPR)
typedef __attribute__((ext_vector_type(4))) float f4v;   // MFMA accum

DEV float u2f(u16 u){
  union { unsigned int i; float f; } t; t.i = ((unsigned int)u) << 16; return t.f;
}
DEV short bfr(float f){
  __hip_bfloat16 h = __float2bfloat16(f);
  short s; __builtin_memcpy(&s, &h, 2); return s;
}
DEV float gelu_tanh(float x){
  float x3 = x * x * x;
  return 0.5f * x * (1.f + tanhf(0.7978845608028654f * (x + 0.044715f * x3)));
}

// ---------------- embedding + positional --------------------------------------
__global__ void k_embed(const int* __restrict__ tokens, const float* __restrict__ emb,
                        const float* __restrict__ pos, float* __restrict__ x){
  int s = blockIdx.x;
  int tok = (s == 0) ? 0 : tokens[s - 1];
  if (tok < 0) tok = 0; if (tok >= VOC) tok = VOC - 1;
  const float* er = emb + (size_t)tok * D;
  const float* pr = pos + (size_t)s * D;
  float* xr = x + (size_t)s * D;
  for (int d = threadIdx.x; d < D; d += blockDim.x)
    xr[d] = er[d] + pr[d];
}

// ---------------- layernorm: 4 rows/block, one wave per row -------------------
__global__ __launch_bounds__(256)
void k_ln(const float* __restrict__ x, const float* __restrict__ sc,
          const float* __restrict__ bi, u16* __restrict__ out){
  int s = blockIdx.x * 4 + (threadIdx.x >> 6), t = threadIdx.x & 63;
  const float* xr = x + (size_t)s * D;
  float v[8]; float sum = 0.f, sq = 0.f;
  #pragma unroll
  for (int e = 0; e < 8; ++e){ v[e] = xr[t + 64 * e]; sum += v[e]; sq += v[e] * v[e]; }
  #pragma unroll
  for (int off = 32; off >= 1; off >>= 1){
    sum += __shfl_down(sum, off, 64);
    sq  += __shfl_down(sq,  off, 64);
  }
  sum = __shfl(sum, 0, 64); sq = __shfl(sq, 0, 64);
  float mu  = sum * (1.f / (float)D);
  float var = sq * (1.f / (float)D) - mu * mu;
  float r = rsqrtf(var + EPSF);
  u16* orow = out + (size_t)s * D;
  #pragma unroll
  for (int e = 0; e < 8; ++e){
    int d = t + 64 * e;
    orow[d] = (u16)bfr((v[e] - mu) * r * sc[d] + bi[d]);
  }
}

// ---------------- weight transpose+convert: fp32 [R][C] -> bf16 [C][R] --------
// (verified round 8) blockIdx.z strides by sStr (src) / dStr (dst).
__global__ __launch_bounds__(256)
void k_wt(const float* __restrict__ src, u16* __restrict__ dst, int R, int C,
          size_t sStr, size_t dStr){
  src += (size_t)blockIdx.z * sStr;
  dst += (size_t)blockIdx.z * dStr;
  __shared__ float tb[32][33];
  int c0 = blockIdx.x * 32, r0 = blockIdx.y * 32;
  int tc = threadIdx.x & 31, tr8 = threadIdx.x >> 5;
  #pragma unroll
  for (int rr = 0; rr < 32; rr += 8)
    tb[rr + tr8][tc] = src[(size_t)(r0 + rr + tr8) * C + c0 + tc];
  __syncthreads();
  #pragma unroll
  for (int rr = 0; rr < 32; rr += 8)
    dst[(size_t)(c0 + rr + tr8) * R + r0 + tc] = (u16)bfr(tb[tc][rr + tr8]);
}

// ================= MFMA GEMM: A bf16 [M][K], Bt bf16 [N][K] ===================
// Round-7-verified loop/LDS layout (GSTR-padded k-groups); B staging is now
// vector s8v loads from Bt, symmetric with A. Tile 128x128, BK=32, 4 waves.
constexpr int GSTR = 1032;   // shorts per k-group (2064 B: +16B pad)

// MODE 0: Cb=bf16(acc*alpha)      1: Cb=bf16(gelu(acc+bias))
// MODE 2: Cf+=acc(+bias)          3: Cf=acc+bias
// MODE 4: qkv fused: Cb=bf16(acc * (col<512 ? alpha : 1))
template<int MODE>
__global__ __launch_bounds__(256)
void k_g2(const u16* __restrict__ A, const u16* __restrict__ Bt,
          const float* __restrict__ bias, float* __restrict__ Cf,
          u16* __restrict__ Cb, int N, int K, float alpha)
{
  __shared__ __align__(16) short As[4 * GSTR];
  __shared__ __align__(16) short Bs[4 * GSTR];
  const int nx = gridDim.x;
  int nwg = nx * gridDim.y;
  int wg = blockIdx.y * nx + blockIdx.x;
  wg = (wg & 7) * (nwg >> 3) + (wg >> 3);        // XCD swizzle (nwg % 8 == 0)
  const int m0 = (wg / nx) * 128, n0 = (wg % nx) * 128;
  const int t = threadIdx.x, lane = t & 63, wv_ = t >> 6;
  const int wr = wv_ >> 1, wc = wv_ & 1, lr = lane & 15, lg = lane >> 4;
  const int sr = t >> 2, sg = t & 3;             // staging: row(0..63)+{0,64}, k-group
  const u16* ap = A  + (size_t)(m0 + sr) * K + sg * 8;
  const u16* bp = Bt + (size_t)(n0 + sr) * K + sg * 8;
  f4v acc[4][4] = {};
  for (int k0 = 0; k0 < K; k0 += 32){
    s8v a0 = *reinterpret_cast<const s8v*>(ap + k0);
    s8v a1 = *reinterpret_cast<const s8v*>(ap + (size_t)64 * K + k0);
    s8v b0 = *reinterpret_cast<const s8v*>(bp + k0);
    s8v b1 = *reinterpret_cast<const s8v*>(bp + (size_t)64 * K + k0);
    __syncthreads();
    *reinterpret_cast<s8v*>(&As[sg * GSTR + sr * 8]) = a0;
    *reinterpret_cast<s8v*>(&As[sg * GSTR + (sr + 64) * 8]) = a1;
    *reinterpret_cast<s8v*>(&Bs[sg * GSTR + sr * 8]) = b0;
    *reinterpret_cast<s8v*>(&Bs[sg * GSTR + (sr + 64) * 8]) = b1;
    __syncthreads();
    s8v af[4], bf2[4];
    #pragma unroll
    for (int fi = 0; fi < 4; ++fi)
      af[fi] = *reinterpret_cast<const s8v*>(&As[lg * GSTR + (wr * 64 + fi * 16 + lr) * 8]);
    #pragma unroll
    for (int fj = 0; fj < 4; ++fj)
      bf2[fj] = *reinterpret_cast<const s8v*>(&Bs[lg * GSTR + (wc * 64 + fj * 16 + lr) * 8]);
    #pragma unroll
    for (int fi = 0; fi < 4; ++fi)
      #pragma unroll
      for (int fj = 0; fj < 4; ++fj)
        acc[fi][fj] = __builtin_amdgcn_mfma_f32_16x16x32_bf16(af[fi], bf2[fj], acc[fi][fj], 0, 0, 0);
  }
  #pragma unroll
  for (int fi = 0; fi < 4; ++fi)
    #pragma unroll
    for (int fj = 0; fj < 4; ++fj)
      #pragma unroll
      for (int r = 0; r < 4; ++r){
        int row = m0 + wr * 64 + fi * 16 + lg * 4 + r;
        int col = n0 + wc * 64 + fj * 16 + lr;
        size_t idx = (size_t)row * N + col;
        float v = acc[fi][fj][r];
        if (MODE == 0)      Cb[idx] = (u16)bfr(v * alpha);
        else if (MODE == 1) Cb[idx] = (u16)bfr(gelu_tanh(v + bias[col]));
        else if (MODE == 2) Cf[idx] += v + (bias ? bias[col] : 0.f);
        else if (MODE == 3) Cf[idx] = v + bias[col];
        else {  // MODE 4: fused qkv, alpha applies to q columns only
          float al = (col < 512) ? alpha : 1.f;
          Cb[idx] = (u16)bfr(v * al);
        }
      }
}

// ---------------- V column mean, two-stage deterministic ----------------------
__global__ __launch_bounds__(256)
void k_vm1(const u16* __restrict__ v, float* __restrict__ part){
  int col = blockIdx.x * 256 + threadIdx.x;       // grid.x = 2 -> 512 cols
  int rb = blockIdx.y;                            // 16 row chunks of 128
  const u16* p = v + (size_t)rb * 128 * QS + col;
  float s = 0.f;
  for (int r = 0; r < 128; ++r) s += u2f(p[(size_t)r * QS]);
  part[rb * 512 + col] = s;
}
__global__ __launch_bounds__(512)
void k_vm2(const float* __restrict__ part, float* __restrict__ vmean){
  int c = threadIdx.x;
  float s = 0.f;
  #pragma unroll
  for (int i = 0; i < 16; ++i) s += part[i * 512 + c];
  vmean[c] = s * (1.f / (float)S);
}

// ---------------- MFMA block-sparse flash attention (verified round 7) --------
// q/k/v now read from the fused qkv buffer with row stride qs.
__global__ __launch_bounds__(256)
void k_mattn(const u16* __restrict__ qp_, const u16* __restrict__ kp_,
             const u16* __restrict__ vp_, int qs, const int* __restrict__ tokens,
             const float* __restrict__ vmean, u16* __restrict__ ob)
{
  const int q0 = blockIdx.x * 64;
  const int h  = blockIdx.y;
  const int B  = q0 >> 7;
  const int half = (q0 >> 6) & 1;
  const int t = threadIdx.x, w = t >> 6, lane = t & 63;
  const int lr = lane & 15, lg = lane >> 4;

  __shared__ __align__(16) u16 Vt[64][40];
  __shared__ __align__(16) u16 Ps[4][16][40];

  const u16* qrow = qp_ + (size_t)(q0 + 16 * w + lr) * qs + h * DH;
  s8v qf0 = *reinterpret_cast<const s8v*>(qrow + lg * 8);
  s8v qf1 = *reinterpret_cast<const s8v*>(qrow + 32 + lg * 8);

  f4v o0 = {}, o1 = {}, o2 = {}, o3 = {};
  float m[4] = {-1e30f, -1e30f, -1e30f, -1e30f};
  float l[4] = {0.f, 0.f, 0.f, 0.f};

  const int vkey = t & 31, vdq = (t >> 5) * 8;
  const int ntiles = B + (half ? 4 : 2);

  for (int tt = 0; tt < ntiles; ++tt){
    int kbase; bool causal;
    if (tt < B){ kbase = tt * 128 + 96; causal = false; }
    else       { kbase = B * 128 + (tt - B) * 32; causal = (kbase >= q0); }

    __syncthreads();
    s8v vv = *reinterpret_cast<const s8v*>(vp_ + (size_t)(kbase + vkey) * qs + h * DH + vdq);
    #pragma unroll
    for (int e = 0; e < 8; ++e) Vt[vdq + e][vkey] = (u16)vv[e];
    __syncthreads();

    f4v s0 = {}, s1 = {};
    const u16* k0p = kp_ + (size_t)(kbase + lr) * qs + h * DH;
    const u16* k1p = kp_ + (size_t)(kbase + 16 + lr) * qs + h * DH;
    s8v kf;
    kf = *reinterpret_cast<const s8v*>(k0p + lg * 8);
    s0 = __builtin_amdgcn_mfma_f32_16x16x32_bf16(qf0, kf, s0, 0, 0, 0);
    kf = *reinterpret_cast<const s8v*>(k0p + 32 + lg * 8);
    s0 = __builtin_amdgcn_mfma_f32_16x16x32_bf16(qf1, kf, s0, 0, 0, 0);
    kf = *reinterpret_cast<const s8v*>(k1p + lg * 8);
    s1 = __builtin_amdgcn_mfma_f32_16x16x32_bf16(qf0, kf, s1, 0, 0, 0);
    kf = *reinterpret_cast<const s8v*>(k1p + 32 + lg * 8);
    s1 = __builtin_amdgcn_mfma_f32_16x16x32_bf16(qf1, kf, s1, 0, 0, 0);

    const int tok0 = tokens[kbase + lr] > 0;
    const int tok1 = tokens[kbase + 16 + lr] > 0;
    #pragma unroll
    for (int r = 0; r < 4; ++r){
      int qg = q0 + 16 * w + 4 * lg + r;
      float a0 = (tok0 && (!causal || kbase + lr <= qg))      ? s0[r] : -1e30f;
      float a1 = (tok1 && (!causal || kbase + 16 + lr <= qg)) ? s1[r] : -1e30f;
      float tm = fmaxf(a0, a1);
      tm = fmaxf(tm, __shfl_xor(tm, 1, 64));
      tm = fmaxf(tm, __shfl_xor(tm, 2, 64));
      tm = fmaxf(tm, __shfl_xor(tm, 4, 64));
      tm = fmaxf(tm, __shfl_xor(tm, 8, 64));
      float mn = fmaxf(m[r], tm);
      bool dead = (mn <= -1e29f);
      float sc = dead ? 1.f : __expf(m[r] - mn);
      float p0 = dead ? 0.f : __expf(a0 - mn);
      float p1 = dead ? 0.f : __expf(a1 - mn);
      l[r] = l[r] * sc + p0 + p1;   // per-lane partial; reduced in epilogue
      m[r] = mn;
      o0[r] *= sc; o1[r] *= sc; o2[r] *= sc; o3[r] *= sc;
      Ps[w][4 * lg + r][lr]      = (u16)bfr(p0);
      Ps[w][4 * lg + r][16 + lr] = (u16)bfr(p1);
    }

    asm volatile("s_waitcnt lgkmcnt(0)" ::: "memory");
    __builtin_amdgcn_sched_barrier(0);
    s8v pf  = *reinterpret_cast<const s8v*>(&Ps[w][lr][lg * 8]);
    s8v vf0 = *reinterpret_cast<const s8v*>(&Vt[lr][lg * 8]);
    s8v vf1 = *reinterpret_cast<const s8v*>(&Vt[16 + lr][lg * 8]);
    s8v vf2 = *reinterpret_cast<const s8v*>(&Vt[32 + lr][lg * 8]);
    s8v vf3 = *reinterpret_cast<const s8v*>(&Vt[48 + lr][lg * 8]);
    o0 = __builtin_amdgcn_mfma_f32_16x16x32_bf16(pf, vf0, o0, 0, 0, 0);
    o1 = __builtin_amdgcn_mfma_f32_16x16x32_bf16(pf, vf1, o1, 0, 0, 0);
    o2 = __builtin_amdgcn_mfma_f32_16x16x32_bf16(pf, vf2, o2, 0, 0, 0);
    o3 = __builtin_amdgcn_mfma_f32_16x16x32_bf16(pf, vf3, o3, 0, 0, 0);
  }

  #pragma unroll
  for (int r = 0; r < 4; ++r){
    float lt = l[r];
    lt += __shfl_xor(lt, 1, 64);
    lt += __shfl_xor(lt, 2, 64);
    lt += __shfl_xor(lt, 4, 64);
    lt += __shfl_xor(lt, 8, 64);
    int qg = q0 + 16 * w + 4 * lg + r;
    u16* orow = ob + (size_t)qg * D + h * DH;
    bool dead = (lt <= 0.f);
    float inv = dead ? 0.f : 1.f / lt;
    orow[lr]      = (u16)bfr(dead ? vmean[h * DH + lr]      : o0[r] * inv);
    orow[16 + lr] = (u16)bfr(dead ? vmean[h * DH + 16 + lr] : o1[r] * inv);
    orow[32 + lr] = (u16)bfr(dead ? vmean[h * DH + 32 + lr] : o2[r] * inv);
    orow[48 + lr] = (u16)bfr(dead ? vmean[h * DH + 48 + lr] : o3[r] * inv);
  }
}

} // anonymous namespace

extern "C" void kernel_launch(void* const* d_in, const int* in_sizes, int n_in,
                              void* d_out, int out_size, void* d_ws, size_t ws_size,
                              hipStream_t stream)
{
  (void)n_in; (void)out_size; (void)ws_size;

  int I_tok=0, I_emb=1, I_pos=2, I_l1s=3, I_l1b=4, I_wq=5, I_wk=6, I_wv=7,
      I_wo=8, I_l2s=9, I_l2b=10, I_w1=11, I_b1=12, I_w2=13, I_b2=14,
      I_lfs=15, I_lfb=16, I_wout=17, I_bout=18;
  if (in_sizes[0] != S){
    I_b1=0;  I_b2=1;  I_bout=2; I_emb=3;  I_l1b=4; I_l1s=5;  I_l2b=6;
    I_l2s=7; I_lfb=8; I_lfs=9;  I_pos=10; I_tok=11; I_w1=12; I_w2=13;
    I_wk=14; I_wo=15; I_wout=16; I_wq=17; I_wv=18;
  }

  const int*   tokens = (const int*)d_in[I_tok];
  const float* emb  = (const float*)d_in[I_emb];
  const float* pos  = (const float*)d_in[I_pos];
  const float* ln1s = (const float*)d_in[I_l1s];
  const float* ln1b = (const float*)d_in[I_l1b];
  const float* wq   = (const float*)d_in[I_wq];
  const float* wk   = (const float*)d_in[I_wk];
  const float* wv   = (const float*)d_in[I_wv];
  const float* wo   = (const float*)d_in[I_wo];
  const float* ln2s = (const float*)d_in[I_l2s];
  const float* ln2b = (const float*)d_in[I_l2b];
  const float* w1   = (const float*)d_in[I_w1];
  const float* b1   = (const float*)d_in[I_b1];
  const float* w2   = (const float*)d_in[I_w2];
  const float* b2   = (const float*)d_in[I_b2];
  const float* lnfs = (const float*)d_in[I_lfs];
  const float* lnfb = (const float*)d_in[I_lfb];
  const float* wout = (const float*)d_in[I_wout];
  const float* bout = (const float*)d_in[I_bout];
  float* outp = (float*)d_out;

  // ws layout (<60 MB; ws>=60MB confirmed by round 8):
  //   x f32 @0 (4MB) | hb @4MB (2MB) | qkvb @6MB (6MB) | ob @12MB (2MB)
  //   gb @14MB (8MB) | vmean @22MB (2KB) | part @22MB+64KB (32KB)
  //   wqkvT @23MB (9MB) | w1T @32MB (12MB) | w2T @44MB (12MB)
  //   woT @56MB (3MB) | woutT @59MB (0.25MB)
  char* ws = (char*)d_ws;
  float* x    = (float*)(ws);
  u16*  hb    = (u16*)(ws + ((size_t)4  << 20));
  u16*  qkvb  = (u16*)(ws + ((size_t)6  << 20));
  u16*  ob    = (u16*)(ws + ((size_t)12 << 20));
  u16*  gb    = (u16*)(ws + ((size_t)14 << 20));
  float* vmean= (float*)(ws + ((size_t)22 << 20));
  float* part = (float*)(ws + ((size_t)22 << 20) + (64 << 10));
  u16*  wqkvT = (u16*)(ws + ((size_t)23 << 20));
  u16*  w1T   = (u16*)(ws + ((size_t)32 << 20));
  u16*  w2T   = (u16*)(ws + ((size_t)44 << 20));
  u16*  woT   = (u16*)(ws + ((size_t)56 << 20));
  u16*  woutT = (u16*)(ws + ((size_t)59 << 20));

  const size_t L512 = (size_t)512 * 512;   // per-layer elements for 512x512 weights
  const size_t LMLP = (size_t)512 * 2048;

  // weight transforms (fp32 [K][N] -> bf16 [N][K]); qkv fused into [1536][512]/layer
  k_wt<<<dim3(16, 16, 6), dim3(256), 0, stream>>>(wq, wqkvT,              512, 512, L512, (size_t)QS * 512);
  k_wt<<<dim3(16, 16, 6), dim3(256), 0, stream>>>(wk, wqkvT + 512 * 512,  512, 512, L512, (size_t)QS * 512);
  k_wt<<<dim3(16, 16, 6), dim3(256), 0, stream>>>(wv, wqkvT + 1024 * 512, 512, 512, L512, (size_t)QS * 512);
  k_wt<<<dim3(16, 16, 6), dim3(256), 0, stream>>>(wo, woT, 512, 512, L512, L512);
  k_wt<<<dim3(64, 16, 6), dim3(256), 0, stream>>>(w1, w1T, 512, 2048, LMLP, LMLP);
  k_wt<<<dim3(16, 64, 6), dim3(256), 0, stream>>>(w2, w2T, 2048, 512, LMLP, LMLP);
  k_wt<<<dim3(8,  16, 1), dim3(256), 0, stream>>>(wout, woutT, 512, 256, 0, 0);

  k_embed<<<dim3(S), dim3(128), 0, stream>>>(tokens, emb, pos, x);

  for (int l = 0; l < NL; ++l){
    k_ln<<<dim3(S/4), dim3(256), 0, stream>>>(x, ln1s + (size_t)l*D, ln1b + (size_t)l*D, hb);
    k_g2<4><<<dim3(12, 16), dim3(256), 0, stream>>>(
        hb, wqkvT + (size_t)l * QS * 512, nullptr, nullptr, qkvb, QS, 512, 0.125f);
    k_vm1<<<dim3(2, 16), dim3(256), 0, stream>>>(qkvb + 1024, part);
    k_vm2<<<dim3(1), dim3(512), 0, stream>>>(part, vmean);
    k_mattn<<<dim3(S/64, H), dim3(256), 0, stream>>>(
        qkvb, qkvb + 512, qkvb + 1024, QS, tokens, vmean, ob);
    k_g2<2><<<dim3(4, 16), dim3(256), 0, stream>>>(
        ob, woT + (size_t)l * L512, nullptr, x, nullptr, 512, 512, 1.f);
    k_ln<<<dim3(S/4), dim3(256), 0, stream>>>(x, ln2s + (size_t)l*D, ln2b + (size_t)l*D, hb);
    k_g2<1><<<dim3(16, 16), dim3(256), 0, stream>>>(
        hb, w1T + (size_t)l * LMLP, b1 + (size_t)l*MLPD, nullptr, gb, MLPD, 512, 1.f);
    k_g2<2><<<dim3(4, 16), dim3(256), 0, stream>>>(
        gb, w2T + (size_t)l * LMLP, b2 + (size_t)l*D, x, nullptr, 512, 2048, 1.f);
  }

  k_ln<<<dim3(S/4), dim3(256), 0, stream>>>(x, lnfs, lnfb, hb);
  k_g2<3><<<dim3(2, 16), dim3(256), 0, stream>>>(
      hb, woutT, bout, outp, nullptr, VOC, 512, 1.f);
}

// Round 10
// 904.422 us; speedup vs baseline: 1.9183x; 1.2012x over previous
//
#include <hip/hip_runtime.h>
#include <hip/hip_bf16.h>
#include <cstdint>
#include <cstddef>

#define DEV __device__ __forceinline__

namespace {

constexpr int S    = 2048;
constexpr int D    = 512;
constexpr int H    = 8;
constexpr int DH   = 64;
constexpr int NL   = 6;
constexpr int MLPD = 2048;
constexpr int VOC  = 256;
constexpr int QS   = 1536;   // fused qkv row stride
constexpr float EPSF = 1e-6f;

typedef unsigned short u16;
typedef __attribute__((ext_vector_type(8))) short s8v;   // 8 x bf16 (4 VGPR)
typedef __attribute__((ext_vector_type(4))) float f4v;   // MFMA accum

DEV float u2f(u16 u){
  union { unsigned int i; float f; } t; t.i = ((unsigned int)u) << 16; return t.f;
}
DEV short bfr(float f){
  __hip_bfloat16 h = __float2bfloat16(f);
  short s; __builtin_memcpy(&s, &h, 2); return s;
}
DEV float gelu_tanh(float x){
  float x3 = x * x * x;
  return 0.5f * x * (1.f + tanhf(0.7978845608028654f * (x + 0.044715f * x3)));
}

// ---------------- embedding + positional --------------------------------------
__global__ void k_embed(const int* __restrict__ tokens, const float* __restrict__ emb,
                        const float* __restrict__ pos, float* __restrict__ x){
  int s = blockIdx.x;
  int tok = (s == 0) ? 0 : tokens[s - 1];
  if (tok < 0) tok = 0; if (tok >= VOC) tok = VOC - 1;
  const float* er = emb + (size_t)tok * D;
  const float* pr = pos + (size_t)s * D;
  float* xr = x + (size_t)s * D;
  for (int d = threadIdx.x; d < D; d += blockDim.x)
    xr[d] = er[d] + pr[d];
}

// ---------------- layernorm: 4 rows/block, one wave per row -------------------
__global__ __launch_bounds__(256)
void k_ln(const float* __restrict__ x, const float* __restrict__ sc,
          const float* __restrict__ bi, u16* __restrict__ out){
  int s = blockIdx.x * 4 + (threadIdx.x >> 6), t = threadIdx.x & 63;
  const float* xr = x + (size_t)s * D;
  float v[8]; float sum = 0.f, sq = 0.f;
  #pragma unroll
  for (int e = 0; e < 8; ++e){ v[e] = xr[t + 64 * e]; sum += v[e]; sq += v[e] * v[e]; }
  #pragma unroll
  for (int off = 32; off >= 1; off >>= 1){
    sum += __shfl_down(sum, off, 64);
    sq  += __shfl_down(sq,  off, 64);
  }
  sum = __shfl(sum, 0, 64); sq = __shfl(sq, 0, 64);
  float mu  = sum * (1.f / (float)D);
  float var = sq * (1.f / (float)D) - mu * mu;
  float r = rsqrtf(var + EPSF);
  u16* orow = out + (size_t)s * D;
  #pragma unroll
  for (int e = 0; e < 8; ++e){
    int d = t + 64 * e;
    orow[d] = (u16)bfr((v[e] - mu) * r * sc[d] + bi[d]);
  }
}

// ---------------- weight transpose+convert: fp32 [R][C] -> bf16 [C][R] --------
__global__ __launch_bounds__(256)
void k_wt(const float* __restrict__ src, u16* __restrict__ dst, int R, int C,
          size_t sStr, size_t dStr){
  src += (size_t)blockIdx.z * sStr;
  dst += (size_t)blockIdx.z * dStr;
  __shared__ float tb[32][33];
  int c0 = blockIdx.x * 32, r0 = blockIdx.y * 32;
  int tc = threadIdx.x & 31, tr8 = threadIdx.x >> 5;
  #pragma unroll
  for (int rr = 0; rr < 32; rr += 8)
    tb[rr + tr8][tc] = src[(size_t)(r0 + rr + tr8) * C + c0 + tc];
  __syncthreads();
  #pragma unroll
  for (int rr = 0; rr < 32; rr += 8)
    dst[(size_t)(c0 + rr + tr8) * R + r0 + tc] = (u16)bfr(tb[tc][rr + tr8]);
}

// ================= direct-from-global MFMA GEMM ===============================
// 1 wave per block; tile (FM*16) x (FN*16); fragments loaded straight from
// A [M][K] and Bt [N][K] (both bf16, row-major along K) with the HW-verified
// lane mapping: A row=fi*16+lr, k=lg*8+e ; B col=fj*16+lr ; C row=fi*16+lg*4+r,
// col=fj*16+lr. No LDS, no barriers -> compiler free to pipeline loads.
// Operands are L2-resident at these shapes; 16-lane groups read 64B-line-exact.
// MODE 1: Cb=bf16(gelu(acc+bias))  2: Cf+=acc(+bias)  3: Cf=acc+bias
// MODE 4: qkv fused: Cb=bf16(acc * (col<512 ? alpha : 1))
template<int FM, int FN, int MODE>
__global__ __launch_bounds__(64)
void k_gd(const u16* __restrict__ A, const u16* __restrict__ Bt,
          const float* __restrict__ bias, float* __restrict__ Cf,
          u16* __restrict__ Cb, int N, int K, float alpha)
{
  const int nx = gridDim.x;
  const int nwg = nx * gridDim.y;
  int wg = blockIdx.y * nx + blockIdx.x;
  wg = (wg & 7) * (nwg >> 3) + (wg >> 3);        // XCD swizzle (nwg % 8 == 0)
  const int m0 = (wg / nx) * (FM * 16), n0 = (wg % nx) * (FN * 16);
  const int lane = threadIdx.x, lr = lane & 15, lg = lane >> 4;
  const u16* ap = A  + (size_t)(m0 + lr) * K + lg * 8;
  const u16* bp = Bt + (size_t)(n0 + lr) * K + lg * 8;
  f4v acc[FM][FN] = {};
  #pragma unroll 2
  for (int k0 = 0; k0 < K; k0 += 32){
    s8v af[FM], bf[FN];
    #pragma unroll
    for (int fi = 0; fi < FM; ++fi)
      af[fi] = *reinterpret_cast<const s8v*>(ap + (size_t)fi * 16 * K + k0);
    #pragma unroll
    for (int fj = 0; fj < FN; ++fj)
      bf[fj] = *reinterpret_cast<const s8v*>(bp + (size_t)fj * 16 * K + k0);
    #pragma unroll
    for (int fi = 0; fi < FM; ++fi)
      #pragma unroll
      for (int fj = 0; fj < FN; ++fj)
        acc[fi][fj] = __builtin_amdgcn_mfma_f32_16x16x32_bf16(af[fi], bf[fj], acc[fi][fj], 0, 0, 0);
  }
  #pragma unroll
  for (int fi = 0; fi < FM; ++fi)
    #pragma unroll
    for (int fj = 0; fj < FN; ++fj)
      #pragma unroll
      for (int r = 0; r < 4; ++r){
        int row = m0 + fi * 16 + lg * 4 + r;
        int col = n0 + fj * 16 + lr;
        size_t idx = (size_t)row * N + col;
        float v = acc[fi][fj][r];
        if (MODE == 1)      Cb[idx] = (u16)bfr(gelu_tanh(v + bias[col]));
        else if (MODE == 2) Cf[idx] += v + (bias ? bias[col] : 0.f);
        else if (MODE == 3) Cf[idx] = v + bias[col];
        else {  // MODE 4
          float al = (col < 512) ? alpha : 1.f;
          Cb[idx] = (u16)bfr(v * al);
        }
      }
}

// ---------------- V column mean, two-stage deterministic ----------------------
__global__ __launch_bounds__(256)
void k_vm1(const u16* __restrict__ v, float* __restrict__ part){
  int col = blockIdx.x * 256 + threadIdx.x;
  int rb = blockIdx.y;
  const u16* p = v + (size_t)rb * 128 * QS + col;
  float s = 0.f;
  for (int r = 0; r < 128; ++r) s += u2f(p[(size_t)r * QS]);
  part[rb * 512 + col] = s;
}
__global__ __launch_bounds__(512)
void k_vm2(const float* __restrict__ part, float* __restrict__ vmean){
  int c = threadIdx.x;
  float s = 0.f;
  #pragma unroll
  for (int i = 0; i < 16; ++i) s += part[i * 512 + c];
  vmean[c] = s * (1.f / (float)S);
}

// ---------------- MFMA block-sparse flash attention (verified round 7/9) ------
__global__ __launch_bounds__(256)
void k_mattn(const u16* __restrict__ qp_, const u16* __restrict__ kp_,
             const u16* __restrict__ vp_, int qs, const int* __restrict__ tokens,
             const float* __restrict__ vmean, u16* __restrict__ ob)
{
  const int q0 = blockIdx.x * 64;
  const int h  = blockIdx.y;
  const int B  = q0 >> 7;
  const int half = (q0 >> 6) & 1;
  const int t = threadIdx.x, w = t >> 6, lane = t & 63;
  const int lr = lane & 15, lg = lane >> 4;

  __shared__ __align__(16) u16 Vt[64][40];
  __shared__ __align__(16) u16 Ps[4][16][40];

  const u16* qrow = qp_ + (size_t)(q0 + 16 * w + lr) * qs + h * DH;
  s8v qf0 = *reinterpret_cast<const s8v*>(qrow + lg * 8);
  s8v qf1 = *reinterpret_cast<const s8v*>(qrow + 32 + lg * 8);

  f4v o0 = {}, o1 = {}, o2 = {}, o3 = {};
  float m[4] = {-1e30f, -1e30f, -1e30f, -1e30f};
  float l[4] = {0.f, 0.f, 0.f, 0.f};

  const int vkey = t & 31, vdq = (t >> 5) * 8;
  const int ntiles = B + (half ? 4 : 2);

  for (int tt = 0; tt < ntiles; ++tt){
    int kbase; bool causal;
    if (tt < B){ kbase = tt * 128 + 96; causal = false; }
    else       { kbase = B * 128 + (tt - B) * 32; causal = (kbase >= q0); }

    __syncthreads();
    s8v vv = *reinterpret_cast<const s8v*>(vp_ + (size_t)(kbase + vkey) * qs + h * DH + vdq);
    #pragma unroll
    for (int e = 0; e < 8; ++e) Vt[vdq + e][vkey] = (u16)vv[e];
    __syncthreads();

    f4v s0 = {}, s1 = {};
    const u16* k0p = kp_ + (size_t)(kbase + lr) * qs + h * DH;
    const u16* k1p = kp_ + (size_t)(kbase + 16 + lr) * qs + h * DH;
    s8v kf;
    kf = *reinterpret_cast<const s8v*>(k0p + lg * 8);
    s0 = __builtin_amdgcn_mfma_f32_16x16x32_bf16(qf0, kf, s0, 0, 0, 0);
    kf = *reinterpret_cast<const s8v*>(k0p + 32 + lg * 8);
    s0 = __builtin_amdgcn_mfma_f32_16x16x32_bf16(qf1, kf, s0, 0, 0, 0);
    kf = *reinterpret_cast<const s8v*>(k1p + lg * 8);
    s1 = __builtin_amdgcn_mfma_f32_16x16x32_bf16(qf0, kf, s1, 0, 0, 0);
    kf = *reinterpret_cast<const s8v*>(k1p + 32 + lg * 8);
    s1 = __builtin_amdgcn_mfma_f32_16x16x32_bf16(qf1, kf, s1, 0, 0, 0);

    const int tok0 = tokens[kbase + lr] > 0;
    const int tok1 = tokens[kbase + 16 + lr] > 0;
    #pragma unroll
    for (int r = 0; r < 4; ++r){
      int qg = q0 + 16 * w + 4 * lg + r;
      float a0 = (tok0 && (!causal || kbase + lr <= qg))      ? s0[r] : -1e30f;
      float a1 = (tok1 && (!causal || kbase + 16 + lr <= qg)) ? s1[r] : -1e30f;
      float tm = fmaxf(a0, a1);
      tm = fmaxf(tm, __shfl_xor(tm, 1, 64));
      tm = fmaxf(tm, __shfl_xor(tm, 2, 64));
      tm = fmaxf(tm, __shfl_xor(tm, 4, 64));
      tm = fmaxf(tm, __shfl_xor(tm, 8, 64));
      float mn = fmaxf(m[r], tm);
      bool dead = (mn <= -1e29f);
      float sc = dead ? 1.f : __expf(m[r] - mn);
      float p0 = dead ? 0.f : __expf(a0 - mn);
      float p1 = dead ? 0.f : __expf(a1 - mn);
      l[r] = l[r] * sc + p0 + p1;
      m[r] = mn;
      o0[r] *= sc; o1[r] *= sc; o2[r] *= sc; o3[r] *= sc;
      Ps[w][4 * lg + r][lr]      = (u16)bfr(p0);
      Ps[w][4 * lg + r][16 + lr] = (u16)bfr(p1);
    }

    asm volatile("s_waitcnt lgkmcnt(0)" ::: "memory");
    __builtin_amdgcn_sched_barrier(0);
    s8v pf  = *reinterpret_cast<const s8v*>(&Ps[w][lr][lg * 8]);
    s8v vf0 = *reinterpret_cast<const s8v*>(&Vt[lr][lg * 8]);
    s8v vf1 = *reinterpret_cast<const s8v*>(&Vt[16 + lr][lg * 8]);
    s8v vf2 = *reinterpret_cast<const s8v*>(&Vt[32 + lr][lg * 8]);
    s8v vf3 = *reinterpret_cast<const s8v*>(&Vt[48 + lr][lg * 8]);
    o0 = __builtin_amdgcn_mfma_f32_16x16x32_bf16(pf, vf0, o0, 0, 0, 0);
    o1 = __builtin_amdgcn_mfma_f32_16x16x32_bf16(pf, vf1, o1, 0, 0, 0);
    o2 = __builtin_amdgcn_mfma_f32_16x16x32_bf16(pf, vf2, o2, 0, 0, 0);
    o3 = __builtin_amdgcn_mfma_f32_16x16x32_bf16(pf, vf3, o3, 0, 0, 0);
  }

  #pragma unroll
  for (int r = 0; r < 4; ++r){
    float lt = l[r];
    lt += __shfl_xor(lt, 1, 64);
    lt += __shfl_xor(lt, 2, 64);
    lt += __shfl_xor(lt, 4, 64);
    lt += __shfl_xor(lt, 8, 64);
    int qg = q0 + 16 * w + 4 * lg + r;
    u16* orow = ob + (size_t)qg * D + h * DH;
    bool dead = (lt <= 0.f);
    float inv = dead ? 0.f : 1.f / lt;
    orow[lr]      = (u16)bfr(dead ? vmean[h * DH + lr]      : o0[r] * inv);
    orow[16 + lr] = (u16)bfr(dead ? vmean[h * DH + 16 + lr] : o1[r] * inv);
    orow[32 + lr] = (u16)bfr(dead ? vmean[h * DH + 32 + lr] : o2[r] * inv);
    orow[48 + lr] = (u16)bfr(dead ? vmean[h * DH + 48 + lr] : o3[r] * inv);
  }
}

} // anonymous namespace

extern "C" void kernel_launch(void* const* d_in, const int* in_sizes, int n_in,
                              void* d_out, int out_size, void* d_ws, size_t ws_size,
                              hipStream_t stream)
{
  (void)n_in; (void)out_size; (void)ws_size;

  int I_tok=0, I_emb=1, I_pos=2, I_l1s=3, I_l1b=4, I_wq=5, I_wk=6, I_wv=7,
      I_wo=8, I_l2s=9, I_l2b=10, I_w1=11, I_b1=12, I_w2=13, I_b2=14,
      I_lfs=15, I_lfb=16, I_wout=17, I_bout=18;
  if (in_sizes[0] != S){
    I_b1=0;  I_b2=1;  I_bout=2; I_emb=3;  I_l1b=4; I_l1s=5;  I_l2b=6;
    I_l2s=7; I_lfb=8; I_lfs=9;  I_pos=10; I_tok=11; I_w1=12; I_w2=13;
    I_wk=14; I_wo=15; I_wout=16; I_wq=17; I_wv=18;
  }

  const int*   tokens = (const int*)d_in[I_tok];
  const float* emb  = (const float*)d_in[I_emb];
  const float* pos  = (const float*)d_in[I_pos];
  const float* ln1s = (const float*)d_in[I_l1s];
  const float* ln1b = (const float*)d_in[I_l1b];
  const float* wq   = (const float*)d_in[I_wq];
  const float* wk   = (const float*)d_in[I_wk];
  const float* wv   = (const float*)d_in[I_wv];
  const float* wo   = (const float*)d_in[I_wo];
  const float* ln2s = (const float*)d_in[I_l2s];
  const float* ln2b = (const float*)d_in[I_l2b];
  const float* w1   = (const float*)d_in[I_w1];
  const float* b1   = (const float*)d_in[I_b1];
  const float* w2   = (const float*)d_in[I_w2];
  const float* b2   = (const float*)d_in[I_b2];
  const float* lnfs = (const float*)d_in[I_lfs];
  const float* lnfb = (const float*)d_in[I_lfb];
  const float* wout = (const float*)d_in[I_wout];
  const float* bout = (const float*)d_in[I_bout];
  float* outp = (float*)d_out;

  // ws layout (same as round 9, verified):
  char* ws = (char*)d_ws;
  float* x    = (float*)(ws);
  u16*  hb    = (u16*)(ws + ((size_t)4  << 20));
  u16*  qkvb  = (u16*)(ws + ((size_t)6  << 20));
  u16*  ob    = (u16*)(ws + ((size_t)12 << 20));
  u16*  gb    = (u16*)(ws + ((size_t)14 << 20));
  float* vmean= (float*)(ws + ((size_t)22 << 20));
  float* part = (float*)(ws + ((size_t)22 << 20) + (64 << 10));
  u16*  wqkvT = (u16*)(ws + ((size_t)23 << 20));
  u16*  w1T   = (u16*)(ws + ((size_t)32 << 20));
  u16*  w2T   = (u16*)(ws + ((size_t)44 << 20));
  u16*  woT   = (u16*)(ws + ((size_t)56 << 20));
  u16*  woutT = (u16*)(ws + ((size_t)59 << 20));

  const size_t L512 = (size_t)512 * 512;
  const size_t LMLP = (size_t)512 * 2048;

  k_wt<<<dim3(16, 16, 6), dim3(256), 0, stream>>>(wq, wqkvT,              512, 512, L512, (size_t)QS * 512);
  k_wt<<<dim3(16, 16, 6), dim3(256), 0, stream>>>(wk, wqkvT + 512 * 512,  512, 512, L512, (size_t)QS * 512);
  k_wt<<<dim3(16, 16, 6), dim3(256), 0, stream>>>(wv, wqkvT + 1024 * 512, 512, 512, L512, (size_t)QS * 512);
  k_wt<<<dim3(16, 16, 6), dim3(256), 0, stream>>>(wo, woT, 512, 512, L512, L512);
  k_wt<<<dim3(64, 16, 6), dim3(256), 0, stream>>>(w1, w1T, 512, 2048, LMLP, LMLP);
  k_wt<<<dim3(16, 64, 6), dim3(256), 0, stream>>>(w2, w2T, 2048, 512, LMLP, LMLP);
  k_wt<<<dim3(8,  16, 1), dim3(256), 0, stream>>>(wout, woutT, 512, 256, 0, 0);

  k_embed<<<dim3(S), dim3(128), 0, stream>>>(tokens, emb, pos, x);

  for (int l = 0; l < NL; ++l){
    k_ln<<<dim3(S/4), dim3(256), 0, stream>>>(x, ln1s + (size_t)l*D, ln1b + (size_t)l*D, hb);
    // qkv: 64x64 tiles, grid (1536/64, 2048/64) = (24, 32) = 768 wg
    k_gd<4,4,4><<<dim3(24, 32), dim3(64), 0, stream>>>(
        hb, wqkvT + (size_t)l * QS * 512, nullptr, nullptr, qkvb, QS, 512, 0.125f);
    k_vm1<<<dim3(2, 16), dim3(256), 0, stream>>>(qkvb + 1024, part);
    k_vm2<<<dim3(1), dim3(512), 0, stream>>>(part, vmean);
    k_mattn<<<dim3(S/64, H), dim3(256), 0, stream>>>(
        qkvb, qkvb + 512, qkvb + 1024, QS, tokens, vmean, ob);
    // wo: 32x64 tiles, grid (512/64, 2048/32) = (8, 64) = 512 wg
    k_gd<2,4,2><<<dim3(8, 64), dim3(64), 0, stream>>>(
        ob, woT + (size_t)l * L512, nullptr, x, nullptr, 512, 512, 1.f);
    k_ln<<<dim3(S/4), dim3(256), 0, stream>>>(x, ln2s + (size_t)l*D, ln2b + (size_t)l*D, hb);
    // w1: 64x64 tiles, grid (2048/64, 2048/64) = (32, 32) = 1024 wg
    k_gd<4,4,1><<<dim3(32, 32), dim3(64), 0, stream>>>(
        hb, w1T + (size_t)l * LMLP, b1 + (size_t)l*MLPD, nullptr, gb, MLPD, 512, 1.f);
    // w2: 32x64 tiles, deep K=2048, grid (8, 64) = 512 wg
    k_gd<2,4,2><<<dim3(8, 64), dim3(64), 0, stream>>>(
        gb, w2T + (size_t)l * LMLP, b2 + (size_t)l*D, x, nullptr, 512, 2048, 1.f);
  }

  k_ln<<<dim3(S/4), dim3(256), 0, stream>>>(x, lnfs, lnfb, hb);
  // logits: 32x64 tiles, grid (256/64, 2048/32) = (4, 64) = 256 wg
  k_gd<2,4,3><<<dim3(4, 64), dim3(64), 0, stream>>>(
      hb, woutT, bout, outp, nullptr, VOC, 512, 1.f);
}

// Round 11
// 854.397 us; speedup vs baseline: 2.0306x; 1.0585x over previous
//
#include <hip/hip_runtime.h>
#include <hip/hip_bf16.h>
#include <cstdint>
#include <cstddef>

#define DEV __device__ __forceinline__

namespace {

constexpr int S    = 2048;
constexpr int D    = 512;
constexpr int H    = 8;
constexpr int DH   = 64;
constexpr int NL   = 6;
constexpr int MLPD = 2048;
constexpr int VOC  = 256;
constexpr int QS   = 1536;   // fused qkv row stride
constexpr float EPSF = 1e-6f;

typedef unsigned short u16;
typedef __attribute__((ext_vector_type(8))) short s8v;   // 8 x bf16 (4 VGPR)
typedef __attribute__((ext_vector_type(4))) float f4v;   // MFMA accum

DEV float u2f(u16 u){
  union { unsigned int i; float f; } t; t.i = ((unsigned int)u) << 16; return t.f;
}
DEV short bfr(float f){
  __hip_bfloat16 h = __float2bfloat16(f);
  short s; __builtin_memcpy(&s, &h, 2); return s;
}
DEV float gelu_tanh(float x){
  float x3 = x * x * x;
  return 0.5f * x * (1.f + tanhf(0.7978845608028654f * (x + 0.044715f * x3)));
}

// ---------------- embedding + positional --------------------------------------
__global__ void k_embed(const int* __restrict__ tokens, const float* __restrict__ emb,
                        const float* __restrict__ pos, float* __restrict__ x){
  int s = blockIdx.x;
  int tok = (s == 0) ? 0 : tokens[s - 1];
  if (tok < 0) tok = 0; if (tok >= VOC) tok = VOC - 1;
  const float* er = emb + (size_t)tok * D;
  const float* pr = pos + (size_t)s * D;
  float* xr = x + (size_t)s * D;
  for (int d = threadIdx.x; d < D; d += blockDim.x)
    xr[d] = er[d] + pr[d];
}

// ---------------- layernorm: 4 rows/block, one wave per row -------------------
__global__ __launch_bounds__(256)
void k_ln(const float* __restrict__ x, const float* __restrict__ sc,
          const float* __restrict__ bi, u16* __restrict__ out){
  int s = blockIdx.x * 4 + (threadIdx.x >> 6), t = threadIdx.x & 63;
  const float* xr = x + (size_t)s * D;
  float v[8]; float sum = 0.f, sq = 0.f;
  #pragma unroll
  for (int e = 0; e < 8; ++e){ v[e] = xr[t + 64 * e]; sum += v[e]; sq += v[e] * v[e]; }
  #pragma unroll
  for (int off = 32; off >= 1; off >>= 1){
    sum += __shfl_down(sum, off, 64);
    sq  += __shfl_down(sq,  off, 64);
  }
  sum = __shfl(sum, 0, 64); sq = __shfl(sq, 0, 64);
  float mu  = sum * (1.f / (float)D);
  float var = sq * (1.f / (float)D) - mu * mu;
  float r = rsqrtf(var + EPSF);
  u16* orow = out + (size_t)s * D;
  #pragma unroll
  for (int e = 0; e < 8; ++e){
    int d = t + 64 * e;
    orow[d] = (u16)bfr((v[e] - mu) * r * sc[d] + bi[d]);
  }
}

// ---------------- weight transpose+convert: fp32 [R][C] -> bf16 [C][R] --------
__global__ __launch_bounds__(256)
void k_wt(const float* __restrict__ src, u16* __restrict__ dst, int R, int C,
          size_t sStr, size_t dStr){
  src += (size_t)blockIdx.z * sStr;
  dst += (size_t)blockIdx.z * dStr;
  __shared__ float tb[32][33];
  int c0 = blockIdx.x * 32, r0 = blockIdx.y * 32;
  int tc = threadIdx.x & 31, tr8 = threadIdx.x >> 5;
  #pragma unroll
  for (int rr = 0; rr < 32; rr += 8)
    tb[rr + tr8][tc] = src[(size_t)(r0 + rr + tr8) * C + c0 + tc];
  __syncthreads();
  #pragma unroll
  for (int rr = 0; rr < 32; rr += 8)
    dst[(size_t)(c0 + rr + tr8) * R + r0 + tc] = (u16)bfr(tb[tc][rr + tr8]);
}

// ================= direct-from-global MFMA GEMM (verified round 10) ===========
// MODE 1: Cb=bf16(gelu(acc+bias))  2: Cf+=acc(+bias)  3: Cf=acc+bias
// MODE 4: qkv fused: Cb=bf16(acc * (col<512 ? alpha : 1))
template<int FM, int FN, int MODE>
__global__ __launch_bounds__(64)
void k_gd(const u16* __restrict__ A, const u16* __restrict__ Bt,
          const float* __restrict__ bias, float* __restrict__ Cf,
          u16* __restrict__ Cb, int N, int K, float alpha)
{
  const int nx = gridDim.x;
  const int nwg = nx * gridDim.y;
  int wg = blockIdx.y * nx + blockIdx.x;
  wg = (wg & 7) * (nwg >> 3) + (wg >> 3);        // XCD swizzle (nwg % 8 == 0)
  const int m0 = (wg / nx) * (FM * 16), n0 = (wg % nx) * (FN * 16);
  const int lane = threadIdx.x, lr = lane & 15, lg = lane >> 4;
  const u16* ap = A  + (size_t)(m0 + lr) * K + lg * 8;
  const u16* bp = Bt + (size_t)(n0 + lr) * K + lg * 8;
  f4v acc[FM][FN] = {};
  #pragma unroll 4
  for (int k0 = 0; k0 < K; k0 += 32){
    s8v af[FM], bf[FN];
    #pragma unroll
    for (int fi = 0; fi < FM; ++fi)
      af[fi] = *reinterpret_cast<const s8v*>(ap + (size_t)fi * 16 * K + k0);
    #pragma unroll
    for (int fj = 0; fj < FN; ++fj)
      bf[fj] = *reinterpret_cast<const s8v*>(bp + (size_t)fj * 16 * K + k0);
    #pragma unroll
    for (int fi = 0; fi < FM; ++fi)
      #pragma unroll
      for (int fj = 0; fj < FN; ++fj)
        acc[fi][fj] = __builtin_amdgcn_mfma_f32_16x16x32_bf16(af[fi], bf[fj], acc[fi][fj], 0, 0, 0);
  }
  #pragma unroll
  for (int fi = 0; fi < FM; ++fi)
    #pragma unroll
    for (int fj = 0; fj < FN; ++fj)
      #pragma unroll
      for (int r = 0; r < 4; ++r){
        int row = m0 + fi * 16 + lg * 4 + r;
        int col = n0 + fj * 16 + lr;
        size_t idx = (size_t)row * N + col;
        float v = acc[fi][fj][r];
        if (MODE == 1)      Cb[idx] = (u16)bfr(gelu_tanh(v + bias[col]));
        else if (MODE == 2) Cf[idx] += v + (bias ? bias[col] : 0.f);
        else if (MODE == 3) Cf[idx] = v + bias[col];
        else {  // MODE 4
          float al = (col < 512) ? alpha : 1.f;
          Cb[idx] = (u16)bfr(v * al);
        }
      }
}

// ---- split-K variant: blockIdx.z selects K-chunk; fp32 partials, no epilogue --
template<int FM, int FN>
__global__ __launch_bounds__(64)
void k_gds(const u16* __restrict__ A, const u16* __restrict__ Bt,
           float* __restrict__ P, int N, int K, int KC)
{
  const int nx = gridDim.x;
  const int nwg = nx * gridDim.y;
  const int M = gridDim.y * (FM * 16);
  int wg = blockIdx.y * nx + blockIdx.x;
  wg = (wg & 7) * (nwg >> 3) + (wg >> 3);        // XCD swizzle (nwg % 8 == 0)
  const int m0 = (wg / nx) * (FM * 16), n0 = (wg % nx) * (FN * 16);
  const int z = blockIdx.z;
  const int lane = threadIdx.x, lr = lane & 15, lg = lane >> 4;
  const u16* ap = A  + (size_t)(m0 + lr) * K + z * KC + lg * 8;
  const u16* bp = Bt + (size_t)(n0 + lr) * K + z * KC + lg * 8;
  P += (size_t)z * M * N;
  f4v acc[FM][FN] = {};
  #pragma unroll 4
  for (int k0 = 0; k0 < KC; k0 += 32){
    s8v af[FM], bf[FN];
    #pragma unroll
    for (int fi = 0; fi < FM; ++fi)
      af[fi] = *reinterpret_cast<const s8v*>(ap + (size_t)fi * 16 * K + k0);
    #pragma unroll
    for (int fj = 0; fj < FN; ++fj)
      bf[fj] = *reinterpret_cast<const s8v*>(bp + (size_t)fj * 16 * K + k0);
    #pragma unroll
    for (int fi = 0; fi < FM; ++fi)
      #pragma unroll
      for (int fj = 0; fj < FN; ++fj)
        acc[fi][fj] = __builtin_amdgcn_mfma_f32_16x16x32_bf16(af[fi], bf[fj], acc[fi][fj], 0, 0, 0);
  }
  #pragma unroll
  for (int fi = 0; fi < FM; ++fi)
    #pragma unroll
    for (int fj = 0; fj < FN; ++fj)
      #pragma unroll
      for (int r = 0; r < 4; ++r){
        int row = m0 + fi * 16 + lg * 4 + r;
        int col = n0 + fj * 16 + lr;
        P[(size_t)row * N + col] = acc[fi][fj][r];
      }
}

// reduce 2 fp32 partials (+optional bias) into residual x, float4-wide
__global__ __launch_bounds__(256)
void k_red(const float* __restrict__ P, const float* __restrict__ bias,
           float* __restrict__ x, int N, size_t MN4)
{
  size_t i = (size_t)blockIdx.x * 256 + threadIdx.x;
  if (i >= MN4) return;
  const float4* p0 = (const float4*)P;
  const float4* p1 = p0 + MN4;
  float4 a = p0[i], b = p1[i];
  float4 xv = ((float4*)x)[i];
  float4 bv = make_float4(0.f, 0.f, 0.f, 0.f);
  if (bias){
    int col4 = (int)(i % (size_t)(N >> 2));
    bv = ((const float4*)bias)[col4];
  }
  xv.x += a.x + b.x + bv.x;
  xv.y += a.y + b.y + bv.y;
  xv.z += a.z + b.z + bv.z;
  xv.w += a.w + b.w + bv.w;
  ((float4*)x)[i] = xv;
}

// ---------------- V column mean, two-stage deterministic ----------------------
__global__ __launch_bounds__(256)
void k_vm1(const u16* __restrict__ v, float* __restrict__ part){
  int col = blockIdx.x * 256 + threadIdx.x;
  int rb = blockIdx.y;
  const u16* p = v + (size_t)rb * 128 * QS + col;
  float s = 0.f;
  for (int r = 0; r < 128; ++r) s += u2f(p[(size_t)r * QS]);
  part[rb * 512 + col] = s;
}
__global__ __launch_bounds__(512)
void k_vm2(const float* __restrict__ part, float* __restrict__ vmean){
  int c = threadIdx.x;
  float s = 0.f;
  #pragma unroll
  for (int i = 0; i < 16; ++i) s += part[i * 512 + c];
  vmean[c] = s * (1.f / (float)S);
}

// ---------------- MFMA block-sparse flash attention (verified round 7/9) ------
__global__ __launch_bounds__(256)
void k_mattn(const u16* __restrict__ qp_, const u16* __restrict__ kp_,
             const u16* __restrict__ vp_, int qs, const int* __restrict__ tokens,
             const float* __restrict__ vmean, u16* __restrict__ ob)
{
  const int q0 = blockIdx.x * 64;
  const int h  = blockIdx.y;
  const int B  = q0 >> 7;
  const int half = (q0 >> 6) & 1;
  const int t = threadIdx.x, w = t >> 6, lane = t & 63;
  const int lr = lane & 15, lg = lane >> 4;

  __shared__ __align__(16) u16 Vt[64][40];
  __shared__ __align__(16) u16 Ps[4][16][40];

  const u16* qrow = qp_ + (size_t)(q0 + 16 * w + lr) * qs + h * DH;
  s8v qf0 = *reinterpret_cast<const s8v*>(qrow + lg * 8);
  s8v qf1 = *reinterpret_cast<const s8v*>(qrow + 32 + lg * 8);

  f4v o0 = {}, o1 = {}, o2 = {}, o3 = {};
  float m[4] = {-1e30f, -1e30f, -1e30f, -1e30f};
  float l[4] = {0.f, 0.f, 0.f, 0.f};

  const int vkey = t & 31, vdq = (t >> 5) * 8;
  const int ntiles = B + (half ? 4 : 2);

  for (int tt = 0; tt < ntiles; ++tt){
    int kbase; bool causal;
    if (tt < B){ kbase = tt * 128 + 96; causal = false; }
    else       { kbase = B * 128 + (tt - B) * 32; causal = (kbase >= q0); }

    __syncthreads();
    s8v vv = *reinterpret_cast<const s8v*>(vp_ + (size_t)(kbase + vkey) * qs + h * DH + vdq);
    #pragma unroll
    for (int e = 0; e < 8; ++e) Vt[vdq + e][vkey] = (u16)vv[e];
    __syncthreads();

    f4v s0 = {}, s1 = {};
    const u16* k0p = kp_ + (size_t)(kbase + lr) * qs + h * DH;
    const u16* k1p = kp_ + (size_t)(kbase + 16 + lr) * qs + h * DH;
    s8v kf;
    kf = *reinterpret_cast<const s8v*>(k0p + lg * 8);
    s0 = __builtin_amdgcn_mfma_f32_16x16x32_bf16(qf0, kf, s0, 0, 0, 0);
    kf = *reinterpret_cast<const s8v*>(k0p + 32 + lg * 8);
    s0 = __builtin_amdgcn_mfma_f32_16x16x32_bf16(qf1, kf, s0, 0, 0, 0);
    kf = *reinterpret_cast<const s8v*>(k1p + lg * 8);
    s1 = __builtin_amdgcn_mfma_f32_16x16x32_bf16(qf0, kf, s1, 0, 0, 0);
    kf = *reinterpret_cast<const s8v*>(k1p + 32 + lg * 8);
    s1 = __builtin_amdgcn_mfma_f32_16x16x32_bf16(qf1, kf, s1, 0, 0, 0);

    const int tok0 = tokens[kbase + lr] > 0;
    const int tok1 = tokens[kbase + 16 + lr] > 0;
    #pragma unroll
    for (int r = 0; r < 4; ++r){
      int qg = q0 + 16 * w + 4 * lg + r;
      float a0 = (tok0 && (!causal || kbase + lr <= qg))      ? s0[r] : -1e30f;
      float a1 = (tok1 && (!causal || kbase + 16 + lr <= qg)) ? s1[r] : -1e30f;
      float tm = fmaxf(a0, a1);
      tm = fmaxf(tm, __shfl_xor(tm, 1, 64));
      tm = fmaxf(tm, __shfl_xor(tm, 2, 64));
      tm = fmaxf(tm, __shfl_xor(tm, 4, 64));
      tm = fmaxf(tm, __shfl_xor(tm, 8, 64));
      float mn = fmaxf(m[r], tm);
      bool dead = (mn <= -1e29f);
      float sc = dead ? 1.f : __expf(m[r] - mn);
      float p0 = dead ? 0.f : __expf(a0 - mn);
      float p1 = dead ? 0.f : __expf(a1 - mn);
      l[r] = l[r] * sc + p0 + p1;
      m[r] = mn;
      o0[r] *= sc; o1[r] *= sc; o2[r] *= sc; o3[r] *= sc;
      Ps[w][4 * lg + r][lr]      = (u16)bfr(p0);
      Ps[w][4 * lg + r][16 + lr] = (u16)bfr(p1);
    }

    asm volatile("s_waitcnt lgkmcnt(0)" ::: "memory");
    __builtin_amdgcn_sched_barrier(0);
    s8v pf  = *reinterpret_cast<const s8v*>(&Ps[w][lr][lg * 8]);
    s8v vf0 = *reinterpret_cast<const s8v*>(&Vt[lr][lg * 8]);
    s8v vf1 = *reinterpret_cast<const s8v*>(&Vt[16 + lr][lg * 8]);
    s8v vf2 = *reinterpret_cast<const s8v*>(&Vt[32 + lr][lg * 8]);
    s8v vf3 = *reinterpret_cast<const s8v*>(&Vt[48 + lr][lg * 8]);
    o0 = __builtin_amdgcn_mfma_f32_16x16x32_bf16(pf, vf0, o0, 0, 0, 0);
    o1 = __builtin_amdgcn_mfma_f32_16x16x32_bf16(pf, vf1, o1, 0, 0, 0);
    o2 = __builtin_amdgcn_mfma_f32_16x16x32_bf16(pf, vf2, o2, 0, 0, 0);
    o3 = __builtin_amdgcn_mfma_f32_16x16x32_bf16(pf, vf3, o3, 0, 0, 0);
  }

  #pragma unroll
  for (int r = 0; r < 4; ++r){
    float lt = l[r];
    lt += __shfl_xor(lt, 1, 64);
    lt += __shfl_xor(lt, 2, 64);
    lt += __shfl_xor(lt, 4, 64);
    lt += __shfl_xor(lt, 8, 64);
    int qg = q0 + 16 * w + 4 * lg + r;
    u16* orow = ob + (size_t)qg * D + h * DH;
    bool dead = (lt <= 0.f);
    float inv = dead ? 0.f : 1.f / lt;
    orow[lr]      = (u16)bfr(dead ? vmean[h * DH + lr]      : o0[r] * inv);
    orow[16 + lr] = (u16)bfr(dead ? vmean[h * DH + 16 + lr] : o1[r] * inv);
    orow[32 + lr] = (u16)bfr(dead ? vmean[h * DH + 32 + lr] : o2[r] * inv);
    orow[48 + lr] = (u16)bfr(dead ? vmean[h * DH + 48 + lr] : o3[r] * inv);
  }
}

} // anonymous namespace

extern "C" void kernel_launch(void* const* d_in, const int* in_sizes, int n_in,
                              void* d_out, int out_size, void* d_ws, size_t ws_size,
                              hipStream_t stream)
{
  (void)n_in; (void)out_size; (void)ws_size;

  int I_tok=0, I_emb=1, I_pos=2, I_l1s=3, I_l1b=4, I_wq=5, I_wk=6, I_wv=7,
      I_wo=8, I_l2s=9, I_l2b=10, I_w1=11, I_b1=12, I_w2=13, I_b2=14,
      I_lfs=15, I_lfb=16, I_wout=17, I_bout=18;
  if (in_sizes[0] != S){
    I_b1=0;  I_b2=1;  I_bout=2; I_emb=3;  I_l1b=4; I_l1s=5;  I_l2b=6;
    I_l2s=7; I_lfb=8; I_lfs=9;  I_pos=10; I_tok=11; I_w1=12; I_w2=13;
    I_wk=14; I_wo=15; I_wout=16; I_wq=17; I_wv=18;
  }

  const int*   tokens = (const int*)d_in[I_tok];
  const float* emb  = (const float*)d_in[I_emb];
  const float* pos  = (const float*)d_in[I_pos];
  const float* ln1s = (const float*)d_in[I_l1s];
  const float* ln1b = (const float*)d_in[I_l1b];
  const float* wq   = (const float*)d_in[I_wq];
  const float* wk   = (const float*)d_in[I_wk];
  const float* wv   = (const float*)d_in[I_wv];
  const float* wo   = (const float*)d_in[I_wo];
  const float* ln2s = (const float*)d_in[I_l2s];
  const float* ln2b = (const float*)d_in[I_l2b];
  const float* w1   = (const float*)d_in[I_w1];
  const float* b1   = (const float*)d_in[I_b1];
  const float* w2   = (const float*)d_in[I_w2];
  const float* b2   = (const float*)d_in[I_b2];
  const float* lnfs = (const float*)d_in[I_lfs];
  const float* lnfb = (const float*)d_in[I_lfb];
  const float* wout = (const float*)d_in[I_wout];
  const float* bout = (const float*)d_in[I_bout];
  float* outp = (float*)d_out;

  // ws layout:
  //   x f32 @0 (4MB) | hb @4MB (2MB) | qkvb @6MB (6MB) | ob @12MB (2MB)
  //   gb @14MB (8MB) | vmean @22MB | part @22MB+64KB
  //   wqkvT @23MB (9MB) | w1T @32MB (12MB) | w2T @44MB (12MB)
  //   woT @56MB (3MB) | woutT @59MB
  //   split-K partials (transient, 8MB each):
  //     wo  partials @14MB (gb region, dead during attention block)
  //     w2  partials @6MB  (qkvb+ob region, dead after wo)
  char* ws = (char*)d_ws;
  float* x    = (float*)(ws);
  u16*  hb    = (u16*)(ws + ((size_t)4  << 20));
  u16*  qkvb  = (u16*)(ws + ((size_t)6  << 20));
  u16*  ob    = (u16*)(ws + ((size_t)12 << 20));
  u16*  gb    = (u16*)(ws + ((size_t)14 << 20));
  float* pWO  = (float*)(ws + ((size_t)14 << 20));   // overlays gb
  float* pW2  = (float*)(ws + ((size_t)6  << 20));   // overlays qkvb+ob
  float* vmean= (float*)(ws + ((size_t)22 << 20));
  float* part = (float*)(ws + ((size_t)22 << 20) + (64 << 10));
  u16*  wqkvT = (u16*)(ws + ((size_t)23 << 20));
  u16*  w1T   = (u16*)(ws + ((size_t)32 << 20));
  u16*  w2T   = (u16*)(ws + ((size_t)44 << 20));
  u16*  woT   = (u16*)(ws + ((size_t)56 << 20));
  u16*  woutT = (u16*)(ws + ((size_t)59 << 20));

  const size_t L512 = (size_t)512 * 512;
  const size_t LMLP = (size_t)512 * 2048;
  const size_t MN4  = (size_t)S * 512 / 4;   // float4 count of a [2048][512] f32

  k_wt<<<dim3(16, 16, 6), dim3(256), 0, stream>>>(wq, wqkvT,              512, 512, L512, (size_t)QS * 512);
  k_wt<<<dim3(16, 16, 6), dim3(256), 0, stream>>>(wk, wqkvT + 512 * 512,  512, 512, L512, (size_t)QS * 512);
  k_wt<<<dim3(16, 16, 6), dim3(256), 0, stream>>>(wv, wqkvT + 1024 * 512, 512, 512, L512, (size_t)QS * 512);
  k_wt<<<dim3(16, 16, 6), dim3(256), 0, stream>>>(wo, woT, 512, 512, L512, L512);
  k_wt<<<dim3(64, 16, 6), dim3(256), 0, stream>>>(w1, w1T, 512, 2048, LMLP, LMLP);
  k_wt<<<dim3(16, 64, 6), dim3(256), 0, stream>>>(w2, w2T, 2048, 512, LMLP, LMLP);
  k_wt<<<dim3(8,  16, 1), dim3(256), 0, stream>>>(wout, woutT, 512, 256, 0, 0);

  k_embed<<<dim3(S), dim3(128), 0, stream>>>(tokens, emb, pos, x);

  for (int l = 0; l < NL; ++l){
    k_ln<<<dim3(S/4), dim3(256), 0, stream>>>(x, ln1s + (size_t)l*D, ln1b + (size_t)l*D, hb);
    // qkv: 64x64 tiles, 768 wg
    k_gd<4,4,4><<<dim3(24, 32), dim3(64), 0, stream>>>(
        hb, wqkvT + (size_t)l * QS * 512, nullptr, nullptr, qkvb, QS, 512, 0.125f);
    k_vm1<<<dim3(2, 16), dim3(256), 0, stream>>>(qkvb + 1024, part);
    k_vm2<<<dim3(1), dim3(512), 0, stream>>>(part, vmean);
    k_mattn<<<dim3(S/64, H), dim3(256), 0, stream>>>(
        qkvb, qkvb + 512, qkvb + 1024, QS, tokens, vmean, ob);
    // wo: split-K=2, 32x64 tiles, (8,64,2) = 1024 wg; partials in gb region
    k_gds<2,4><<<dim3(8, 64, 2), dim3(64), 0, stream>>>(
        ob, woT + (size_t)l * L512, pWO, 512, 512, 256);
    k_red<<<dim3((unsigned)(MN4 / 256)), dim3(256), 0, stream>>>(
        pWO, nullptr, x, 512, MN4);
    k_ln<<<dim3(S/4), dim3(256), 0, stream>>>(x, ln2s + (size_t)l*D, ln2b + (size_t)l*D, hb);
    // w1: 64x64 tiles, 1024 wg
    k_gd<4,4,1><<<dim3(32, 32), dim3(64), 0, stream>>>(
        hb, w1T + (size_t)l * LMLP, b1 + (size_t)l*MLPD, nullptr, gb, MLPD, 512, 1.f);
    // w2: split-K=2, 32x64 tiles, (8,64,2) = 1024 wg; partials in qkvb+ob region
    k_gds<2,4><<<dim3(8, 64, 2), dim3(64), 0, stream>>>(
        gb, w2T + (size_t)l * LMLP, pW2, 512, 2048, 1024);
    k_red<<<dim3((unsigned)(MN4 / 256)), dim3(256), 0, stream>>>(
        pW2, b2 + (size_t)l*D, x, 512, MN4);
  }

  k_ln<<<dim3(S/4), dim3(256), 0, stream>>>(x, lnfs, lnfb, hb);
  // logits: 32x64 tiles, 256 wg
  k_gd<2,4,3><<<dim3(4, 64), dim3(64), 0, stream>>>(
      hb, woutT, bout, outp, nullptr, VOC, 512, 1.f);
}